// Round 4
// baseline (17131.026 us; speedup 1.0000x reference)
//
#include <hip/hip_runtime.h>

constexpr int BB = 32;
constexpr int TT = 512;
constexpr size_t MSZ = (size_t)BB * TT * 128;              // one embedding array (floats)
constexpr size_t M_OFF = 0;                                // 3 * MSZ
constexpr size_t MASK_OFF = 3 * MSZ;                       // 3*B*T ints
constexpr size_t SUM_OFF = MASK_OFF + (size_t)3 * BB * TT; // 4 * MSZ
constexpr size_t WHH_OFF = SUM_OFF + 4 * MSZ;              // 256*1024 floats [k][hid][gate]
constexpr size_t WIH_OFF = WHH_OFF + (size_t)256 * 1024;   // 256*1024 floats [k][hid][gate]
constexpr size_t BIAS_OFF = WIH_OFF + (size_t)256 * 1024;  // 1024 floats [hid][gate]
constexpr size_t FSEL_OFF = BIAS_OFF + 1024;               // 128*256 floats
constexpr size_t STATE_OFF = FSEL_OFF + (size_t)128 * 256; // h(32768) + c(32768)
constexpr size_t XGBUF_OFF = STATE_OFF + 65536;            // CH*128*1024 floats (chunked x-gates)

typedef float v2f __attribute__((ext_vector_type(2)));

__device__ __forceinline__ float sigm(float x) {
  return __builtin_amdgcn_rcpf(1.f + __builtin_amdgcn_exp2f(-1.44269504f * x));
}
__device__ __forceinline__ float tanhfast(float x) {
  float e = __builtin_amdgcn_exp2f(2.88539008f * x);
  return 1.f - 2.f * __builtin_amdgcn_rcpf(e + 1.f);
}
__device__ __forceinline__ float leaky(float x) { return x >= 0.f ? x : 0.1f * x; }

// sum across the 4 lanes of a quad (k-quarters) via DPP quad_perm — no LDS
__device__ __forceinline__ float quad_sum(float x) {
  x += __int_as_float(__builtin_amdgcn_mov_dpp(__float_as_int(x), 0xB1, 0xF, 0xF, true));
  x += __int_as_float(__builtin_amdgcn_mov_dpp(__float_as_int(x), 0x4E, 0xF, 0xF, true));
  return x;
}

__global__ __launch_bounds__(256) void embed_kernel(
    const float* __restrict__ a, const float* __restrict__ t,
    const float* __restrict__ n, const float* __restrict__ Wm,
    const float* __restrict__ bm, float* __restrict__ ws) {
  int idx = blockIdx.x * 256 + threadIdx.x;   // < 3*B*T*128
  int h = idx & 127;
  int bt = idx >> 7;
  int traj = bt / (BB * TT);
  int r = bt - traj * (BB * TT);
  const float* src = traj == 0 ? a : (traj == 1 ? t : n);
  float x0 = src[r * 4 + 0], x1 = src[r * 4 + 1];
  float v = x0 * Wm[2 * h] + x1 * Wm[2 * h + 1] + bm[h];
  ws[M_OFF + (size_t)traj * MSZ + (size_t)r * 128 + h] = leaky(v);
}

__global__ __launch_bounds__(256) void mask_kernel(
    const float* __restrict__ a, const float* __restrict__ t,
    const float* __restrict__ n, float* __restrict__ ws) {
  int idx = blockIdx.x * 256 + threadIdx.x;   // < 3*B*T
  int traj = idx / (BB * TT);
  int r = idx - traj * (BB * TT);
  const float* src = traj == 0 ? a : (traj == 1 ? t : n);
  float gx = src[r * 4 + 2], gy = src[r * 4 + 3];
  ((int*)(ws + MASK_OFF))[idx] = (gy * 128.f + gx - 257.f) >= 0.5f ? 1 : 0;
}

// transpose Whh and Wih to [k][hid][gate] (torch gate order i,f,g,o); fold biases
__global__ __launch_bounds__(256) void wt_kernel(
    const float* __restrict__ Wih, const float* __restrict__ Whh,
    const float* __restrict__ bih, const float* __restrict__ bhh,
    float* __restrict__ ws) {
  int idx = blockIdx.x * 256 + threadIdx.x;  // < 525312
  if (idx < 262144) {
    int k = idx >> 10;
    int rest = idx & 1023;
    int hid = rest >> 2, g = rest & 3;
    ws[WHH_OFF + idx] = Whh[(g * 256 + hid) * 256 + k];
  } else if (idx < 524288) {
    int j = idx - 262144;
    int k = j >> 10;
    int rest = j & 1023;
    int hid = rest >> 2, g = rest & 3;
    ws[WIH_OFF + j] = Wih[(g * 256 + hid) * 256 + k];
  } else if (idx < 525312) {
    int j = idx - 524288;
    int hid = j >> 2, g = j & 3;
    ws[BIAS_OFF + j] = bih[g * 256 + hid] + bhh[g * 256 + hid];
  }
}

// one WG per (job, batch, 16-row t-tile); job 0..3 = L0..L3 source/dest pairs
__global__ __launch_bounds__(256) void attn_kernel(float* __restrict__ ws) {
  __shared__ float srcL[16][129];
  __shared__ float dtile[128][34];
  __shared__ float scoresL[16][514];
  __shared__ float rowscaleL[16];
  __shared__ int maskD[32];
  __shared__ int maskS[16];

  int tid = threadIdx.x;
  int job = blockIdx.x >> 10;
  int rem = blockIdx.x & 1023;
  int b = rem >> 5, ttile = rem & 31;
  int t0 = ttile * 16;
  int srcTr = (job == 1) ? 1 : ((job == 3) ? 2 : 0);
  int dstTr = (job == 0) ? 1 : ((job == 2) ? 2 : 0);
  const float* msrc = ws + M_OFF + (size_t)srcTr * MSZ + (size_t)b * TT * 128;
  const float* mdst = ws + M_OFF + (size_t)dstTr * MSZ + (size_t)b * TT * 128;
  const int* maskbase = (const int*)(ws + MASK_OFF);
  const int* smask = maskbase + srcTr * BB * TT + b * TT;
  const int* dmask = maskbase + dstTr * BB * TT + b * TT;
  float* out = ws + SUM_OFF + (size_t)job * MSZ + (size_t)b * TT * 128;

  for (int i = 0; i < 8; i++) {
    int idx = i * 256 + tid;
    int tr = idx >> 7, k = idx & 127;
    srcL[tr][k] = msrc[(size_t)(t0 + tr) * 128 + k];
  }
  if (tid < 16) maskS[tid] = smask[t0 + tid];
  __syncthreads();

  int s2 = tid & 15, trr = tid >> 4;
  for (int st = 0; st < 16; st++) {
    int s0 = st * 32;
    for (int i = 0; i < 16; i++) {
      int idx = i * 256 + tid;
      int s = idx >> 7, k = idx & 127;
      dtile[k][s] = mdst[(size_t)(s0 + s) * 128 + k];
    }
    if (tid < 32) maskD[tid] = dmask[s0 + tid];
    __syncthreads();
    float d0 = 0.f, d1 = 0.f;
#pragma unroll 8
    for (int k = 0; k < 128; k++) {
      float sv = srcL[trr][k];
      float2 dv = *(const float2*)&dtile[k][2 * s2];
      d0 += sv * dv.x;
      d1 += sv * dv.y;
    }
    scoresL[trr][s0 + 2 * s2]     = maskD[2 * s2]     ? d0 : -1e9f;
    scoresL[trr][s0 + 2 * s2 + 1] = maskD[2 * s2 + 1] ? d1 : -1e9f;
    __syncthreads();
  }

  {
    int r = tid >> 4, j = tid & 15;
    float mx = -3.0e38f;
    for (int i = 0; i < 32; i++) mx = fmaxf(mx, scoresL[r][j + 16 * i]);
    for (int m = 1; m < 16; m <<= 1) mx = fmaxf(mx, __shfl_xor(mx, m, 64));
    float den = 0.f;
    for (int i = 0; i < 32; i++) {
      float p = __builtin_amdgcn_exp2f((scoresL[r][j + 16 * i] - mx) * 1.44269504f);
      scoresL[r][j + 16 * i] = p;
      den += p;
    }
    for (int m = 1; m < 16; m <<= 1) den += __shfl_xor(den, m, 64);
    if (j == 0) rowscaleL[r] = (maskS[r] && mx > -5e8f) ? (1.f / den) : 0.f;
  }
  __syncthreads();

  int kk = tid & 127, tix = tid >> 7;
  float acc[8];
#pragma unroll
  for (int u = 0; u < 8; u++) acc[u] = 0.f;
  for (int st = 0; st < 16; st++) {
    int s0 = st * 32;
    for (int i = 0; i < 16; i++) {
      int idx = i * 256 + tid;
      int s = idx >> 7, k = idx & 127;
      dtile[k][s] = mdst[(size_t)(s0 + s) * 128 + k];
    }
    __syncthreads();
    for (int s = 0; s < 32; s += 2) {
      float2 dv = *(const float2*)&dtile[kk][s];
#pragma unroll
      for (int u = 0; u < 8; u++) {
        float2 p = *(const float2*)&scoresL[tix * 8 + u][s0 + s];
        acc[u] += p.x * dv.x + p.y * dv.y;
      }
    }
    __syncthreads();
  }
#pragma unroll
  for (int u = 0; u < 8; u++) {
    int tr = tix * 8 + u;
    out[(size_t)(t0 + tr) * 128 + kk] = acc[u] * rowscaleL[tr];
  }
}

// chunked x-gate GEMM: xg[seq][t-tc0][1024] = xcat @ WihT + bias for t in [tc0, tc0+CH)
// thread covers cols {c0..c0+3} and {c0+128..c0+131}, c0=(tid&31)*4 -> contiguous b128 reads
__global__ __launch_bounds__(256) void xg_kernel(
    float* __restrict__ ws, int tc0, int CH,
    const int* __restrict__ la, const int* __restrict__ lt, const int* __restrict__ ln) {
  __shared__ float aT[32][68];
  __shared__ float bL[32][256];
  int tid = threadIdx.x;
  int bx = blockIdx.x;
  int tt4 = (CH >> 6) << 2;       // tiles*4 per seq
  int seq = bx / tt4;
  int rem = bx - seq * tt4;
  int tt = rem >> 2;
  int nc = rem & 3;
  int t0 = tc0 + tt * 64;
  int l = seq >> 5, b = seq & 31;
  const int* lens = (l == 1) ? lt : ((l == 3) ? ln : la);
  if (t0 >= lens[b]) return;      // beyond this sequence's length: dead work
  int srcTr = (l == 1) ? 1 : ((l == 3) ? 2 : 0);
  const float* xrow = ws + M_OFF + (size_t)srcTr * MSZ + (size_t)b * TT * 128;
  const float* srow = ws + SUM_OFF + (size_t)l * MSZ + (size_t)b * TT * 128;

  int r0 = tid >> 5;
  int c0 = (tid & 31) * 4;

  float acc[8][8];
#pragma unroll
  for (int i = 0; i < 8; i++)
#pragma unroll
    for (int j = 0; j < 8; j++) acc[i][j] = 0.f;

  for (int kc = 0; kc < 8; kc++) {
    int kbase = kc * 32;
    __syncthreads();
#pragma unroll
    for (int i = 0; i < 8; i++) {
      int idx = i * 256 + tid;
      int m = idx >> 5, kk = idx & 31;
      float v;
      if (kbase < 128) {
        v = xrow[(size_t)(t0 + m) * 128 + kbase + kk];
      } else {
        int k2 = kbase + kk - 128;
        v = xrow[(size_t)(t0 + m) * 128 + k2] - srow[(size_t)(t0 + m) * 128 + k2];
      }
      aT[kk][m] = v;
    }
#pragma unroll
    for (int i = 0; i < 32; i++) {
      int idx = i * 256 + tid;
      int kk = idx >> 8, n = idx & 255;
      bL[kk][n] = ws[WIH_OFF + (size_t)(kbase + kk) * 1024 + nc * 256 + n];
    }
    __syncthreads();
#pragma unroll 2
    for (int kk = 0; kk < 32; kk++) {
      float4 a0 = *(const float4*)&aT[kk][r0 * 8];
      float4 a1 = *(const float4*)&aT[kk][r0 * 8 + 4];
      float4 b0 = *(const float4*)&bL[kk][c0];
      float4 b1 = *(const float4*)&bL[kk][c0 + 128];
      float av[8] = {a0.x, a0.y, a0.z, a0.w, a1.x, a1.y, a1.z, a1.w};
      float bv[8] = {b0.x, b0.y, b0.z, b0.w, b1.x, b1.y, b1.z, b1.w};
#pragma unroll
      for (int i = 0; i < 8; i++)
#pragma unroll
        for (int j = 0; j < 8; j++) acc[i][j] += av[i] * bv[j];
    }
  }

  float4 bias0 = *(const float4*)&ws[BIAS_OFF + nc * 256 + c0];
  float4 bias1 = *(const float4*)&ws[BIAS_OFF + nc * 256 + c0 + 128];
#pragma unroll
  for (int i = 0; i < 8; i++) {
    int tl = t0 - tc0 + r0 * 8 + i;
    float* o = ws + XGBUF_OFF + ((size_t)seq * CH + tl) * 1024 + nc * 256 + c0;
    float4 v0 = {acc[i][0] + bias0.x, acc[i][1] + bias0.y,
                 acc[i][2] + bias0.z, acc[i][3] + bias0.w};
    float4 v1 = {acc[i][4] + bias1.x, acc[i][5] + bias1.y,
                 acc[i][6] + bias1.z, acc[i][7] + bias1.w};
    *(float4*)o = v0;
    *(float4*)(o + 128) = v1;
  }
}

// one batch-processing step of the weight stream: prefetch next 8 k's while FMA'ing current
#define REC_BATCH(CUR, NXT, KB)                                             \
  {                                                                         \
    if ((KB) < 7) {                                                         \
      _Pragma("unroll")                                                     \
      for (int u = 0; u < 8; u++)                                           \
        NXT[u] = *(const float4*)(wq + (((KB) + 1) * 8 + u) * 1024);        \
    }                                                                       \
    float4 pa0 = *(const float4*)(hApt + (KB) * 8);                         \
    float4 pa1 = *(const float4*)(hApt + (KB) * 8 + 4);                     \
    float4 pb0 = *(const float4*)(hBpt + (KB) * 8);                         \
    float4 pb1 = *(const float4*)(hBpt + (KB) * 8 + 4);                     \
    float ha[8] = {pa0.x, pa0.y, pa0.z, pa0.w, pa1.x, pa1.y, pa1.z, pa1.w}; \
    float hb[8] = {pb0.x, pb0.y, pb0.z, pb0.w, pb1.x, pb1.y, pb1.z, pb1.w}; \
    _Pragma("unroll")                                                       \
    for (int u = 0; u < 8; u++) {                                           \
      v2f wif = {CUR[u].x, CUR[u].y};                                       \
      v2f wgo = {CUR[u].z, CUR[u].w};                                       \
      v2f has = {ha[u], ha[u]};                                             \
      v2f hbs = {hb[u], hb[u]};                                             \
      aifA += wif * has; agoA += wgo * has;                                 \
      aifB += wif * hbs; agoB += wgo * hbs;                                 \
    }                                                                       \
  }

// recurrence over one chunk: 64 WGs x 1024 threads, 2 seqs/WG.
// thread = (hid, ks = k-quarter). Quad (DPP) reduction; pk-fma; 8-deep prefetch.
__global__ __launch_bounds__(1024, 4) void rec3_kernel(
    float* __restrict__ ws, const int* __restrict__ la,
    const int* __restrict__ lt, const int* __restrict__ ln,
    int t0c, int CH) {
  __shared__ float hbuf[2][2][256];
  int tid = threadIdx.x;
  int hid = tid >> 2;
  int ks = tid & 3;
  int s0 = blockIdx.x * 2;
  int l = s0 >> 5;                 // pair never straddles an l-group
  int b0 = s0 & 31;
  const int* lens = (l == 1) ? lt : ((l == 3) ? ln : la);
  int lenA = lens[b0], lenB = lens[b0 + 1];
  int tend = min(CH, max(lenA, lenB) - t0c);
  if (tend <= 0) return;

  float* sh = ws + STATE_OFF;              // h state [128][256]
  float* sc = ws + STATE_OFF + 32768;      // c state [128][256]
  float cA, cB, hA, hB;
  if (t0c == 0) {
    cA = 0.f; cB = 0.f; hA = 0.f; hB = 0.f;
  } else {
    cA = sc[(size_t)s0 * 256 + hid];
    cB = sc[(size_t)(s0 + 1) * 256 + hid];
    hA = sh[(size_t)s0 * 256 + hid];
    hB = sh[(size_t)(s0 + 1) * 256 + hid];
  }
  if (ks == 0) {
    hbuf[0][0][hid] = hA;
    hbuf[0][1][hid] = hB;
  }
  const float* wq = ws + WHH_OFF + ((size_t)(ks * 64) << 10) + (hid << 2);
  const float* xgA = ws + XGBUF_OFF + ((size_t)s0 * CH) * 1024 + (hid << 2);
  const float* xgB = xgA + (size_t)CH * 1024;
  float* foutA = ws + FSEL_OFF + (size_t)s0 * 256;
  float* foutB = foutA + 256;
  __syncthreads();

  int pp = 0;
  for (int tl = 0; tl < tend; tl++) {
    float4 w0[8], w1[8];
#pragma unroll
    for (int u = 0; u < 8; u++) w0[u] = *(const float4*)(wq + u * 1024);
    float4 xa = *(const float4*)(xgA + (size_t)tl * 1024);
    float4 xb = *(const float4*)(xgB + (size_t)tl * 1024);
    v2f aifA = {0.f, 0.f}, agoA = {0.f, 0.f};
    v2f aifB = {0.f, 0.f}, agoB = {0.f, 0.f};
    const float* hApt = &hbuf[pp][0][ks * 64];
    const float* hBpt = &hbuf[pp][1][ks * 64];
    REC_BATCH(w0, w1, 0)
    REC_BATCH(w1, w0, 1)
    REC_BATCH(w0, w1, 2)
    REC_BATCH(w1, w0, 3)
    REC_BATCH(w0, w1, 4)
    REC_BATCH(w1, w0, 5)
    REC_BATCH(w0, w1, 6)
    REC_BATCH(w1, w0, 7)

    float iA = quad_sum(aifA.x) + xa.x;
    float fA = quad_sum(aifA.y) + xa.y;
    float gA = quad_sum(agoA.x) + xa.z;
    float oA = quad_sum(agoA.y) + xa.w;
    float iB = quad_sum(aifB.x) + xb.x;
    float fB = quad_sum(aifB.y) + xb.y;
    float gB = quad_sum(agoB.x) + xb.z;
    float oB = quad_sum(agoB.y) + xb.w;

    cA = sigm(fA) * cA + sigm(iA) * tanhfast(gA);
    hA = sigm(oA) * tanhfast(cA);
    cB = sigm(fB) * cB + sigm(iB) * tanhfast(gB);
    hB = sigm(oB) * tanhfast(cB);

    if (ks == 0) {
      hbuf[pp ^ 1][0][hid] = hA;
      hbuf[pp ^ 1][1][hid] = hB;
      int t = t0c + tl;
      if (t == lenA - 1) foutA[hid] = hA;
      if (t == lenB - 1) foutB[hid] = hB;
    }
    __syncthreads();
    pp ^= 1;
  }
  if (ks == 0) {
    sh[(size_t)s0 * 256 + hid] = hA;
    sh[(size_t)(s0 + 1) * 256 + hid] = hB;
    sc[(size_t)s0 * 256 + hid] = cA;
    sc[(size_t)(s0 + 1) * 256 + hid] = cB;
  }
}

// fallback if ws too small for chunked xg: streams Wih+Whh per step (K=512)
__global__ __launch_bounds__(512, 2) void rec_fb_kernel(
    float* __restrict__ ws, const int* __restrict__ la,
    const int* __restrict__ lt, const int* __restrict__ ln) {
  __shared__ float hL[2][256];
  __shared__ float xL[2][256];
  int tid = threadIdx.x;
  int sl = tid >> 8;
  int hid = tid & 255;
  int seq = blockIdx.x * 2 + sl;
  int l = seq >> 5, b = seq & 31;
  int srcTr = (l == 1) ? 1 : ((l == 3) ? 2 : 0);
  const float* xrow = ws + M_OFF + (size_t)srcTr * MSZ + (size_t)b * TT * 128;
  const float* srow = ws + SUM_OFF + (size_t)l * MSZ + (size_t)b * TT * 128;
  const int* lens = (l == 1) ? lt : ((l == 3) ? ln : la);
  int b0 = b & ~1;
  int mylen = lens[b];
  int tmax = max(lens[b0], lens[b0 + 1]);
  const float* wh = ws + WHH_OFF + (hid << 2);
  const float* wi = ws + WIH_OFF + (hid << 2);
  float4 biasv = *(const float4*)&ws[BIAS_OFF + (hid << 2)];
  float c = 0.f;
  hL[sl][hid] = 0.f;
  xL[sl][hid] = hid < 128 ? xrow[hid] : xrow[hid - 128] - srow[hid - 128];
  __syncthreads();
  float* fout = ws + FSEL_OFF + (size_t)seq * 256;

  for (int t = 0; t < tmax; t++) {
    float gi = biasv.x, gf = biasv.y, gg = biasv.z, go = biasv.w;
    {
      const float* hp = &hL[sl][0];
#pragma unroll 4
      for (int k = 0; k < 256; k += 4) {
        float4 hv = *(const float4*)(hp + k);
        const float* w = wh + (size_t)k * 1024;
        float4 w0 = *(const float4*)(w);
        float4 w1 = *(const float4*)(w + 1024);
        float4 w2 = *(const float4*)(w + 2048);
        float4 w3 = *(const float4*)(w + 3072);
        gi += hv.x * w0.x + hv.y * w1.x + hv.z * w2.x + hv.w * w3.x;
        gf += hv.x * w0.y + hv.y * w1.y + hv.z * w2.y + hv.w * w3.y;
        gg += hv.x * w0.z + hv.y * w1.z + hv.z * w2.z + hv.w * w3.z;
        go += hv.x * w0.w + hv.y * w1.w + hv.z * w2.w + hv.w * w3.w;
      }
    }
    {
      const float* xp = &xL[sl][0];
#pragma unroll 4
      for (int k = 0; k < 256; k += 4) {
        float4 xv = *(const float4*)(xp + k);
        const float* w = wi + (size_t)k * 1024;
        float4 w0 = *(const float4*)(w);
        float4 w1 = *(const float4*)(w + 1024);
        float4 w2 = *(const float4*)(w + 2048);
        float4 w3 = *(const float4*)(w + 3072);
        gi += xv.x * w0.x + xv.y * w1.x + xv.z * w2.x + xv.w * w3.x;
        gf += xv.x * w0.y + xv.y * w1.y + xv.z * w2.y + xv.w * w3.y;
        gg += xv.x * w0.z + xv.y * w1.z + xv.z * w2.z + xv.w * w3.z;
        go += xv.x * w0.w + xv.y * w1.w + xv.z * w2.w + xv.w * w3.w;
      }
    }
    float c_new = sigm(gf) * c + sigm(gi) * tanhfast(gg);
    c = c_new;
    float h = sigm(go) * tanhfast(c_new);
    __syncthreads();
    hL[sl][hid] = h;
    if (t + 1 < TT) {
      int tn = t + 1;
      xL[sl][hid] = hid < 128 ? xrow[tn * 128 + hid]
                              : xrow[tn * 128 + hid - 128] - srow[tn * 128 + hid - 128];
    }
    if (t == mylen - 1) fout[hid] = h;
    __syncthreads();
  }
}

__global__ __launch_bounds__(256) void finish_kernel(
    const float* __restrict__ ws, const float* __restrict__ W1,
    const float* __restrict__ b1, const float* __restrict__ W2,
    const float* __restrict__ b2, const float* __restrict__ W3,
    const float* __restrict__ b3, float* __restrict__ out) {
  __shared__ float oL[256];
  __shared__ float wsum[4];
  int tid = threadIdx.x;
  int p = blockIdx.x >> 5, b = blockIdx.x & 31;
  const float* fa = ws + FSEL_OFF + (size_t)((2 * p) * 32 + b) * 256;
  const float* fb = ws + FSEL_OFF + (size_t)((2 * p + 1) * 32 + b) * 256;
  oL[tid] = fa[tid];
  __syncthreads();
  float a1 = b1[tid], a2 = b2[tid], a3 = b3[tid];
  const float* w1r = W1 + tid * 256;
  const float* w2r = W2 + tid * 256;
  const float* w3r = W3 + tid * 256;
  for (int k = 0; k < 256; k++) {
    float ov = oL[k];
    a1 += ov * w1r[k];
    a2 += ov * w2r[k];
    a3 += ov * w3r[k];
  }
  float cg = sigm(a1) * leaky(a2);
  float res = oL[tid] + sigm(a3) * leaky(cg);
  float d = res - fb[tid] + 1e-6f;
  float sq = d * d;
  for (int m = 32; m >= 1; m >>= 1) sq += __shfl_down(sq, m, 64);
  if ((tid & 63) == 0) wsum[tid >> 6] = sq;
  __syncthreads();
  if (tid == 0) {
    float s = wsum[0] + wsum[1] + wsum[2] + wsum[3];
    out[p * BB + b] = expf(sqrtf(s));
  }
}

extern "C" void kernel_launch(void* const* d_in, const int* in_sizes, int n_in,
                              void* d_out, int out_size, void* d_ws, size_t ws_size,
                              hipStream_t stream) {
  const float* anchor = (const float*)d_in[0];
  const float* trajs = (const float*)d_in[1];
  const float* negat = (const float*)d_in[2];
  const int* la = (const int*)d_in[3];
  const int* lt = (const int*)d_in[4];
  const int* ln = (const int*)d_in[5];
  const float* Wm = (const float*)d_in[6];
  const float* bm = (const float*)d_in[7];
  const float* Wih = (const float*)d_in[8];
  const float* Whh = (const float*)d_in[9];
  const float* bih = (const float*)d_in[10];
  const float* bhh = (const float*)d_in[11];
  const float* W1 = (const float*)d_in[12];
  const float* b1 = (const float*)d_in[13];
  const float* W2 = (const float*)d_in[14];
  const float* b2 = (const float*)d_in[15];
  const float* W3 = (const float*)d_in[16];
  const float* b3 = (const float*)d_in[17];
  float* ws = (float*)d_ws;
  float* out = (float*)d_out;

  embed_kernel<<<(3 * BB * TT * 128) / 256, 256, 0, stream>>>(anchor, trajs, negat, Wm, bm, ws);
  mask_kernel<<<(3 * BB * TT) / 256, 256, 0, stream>>>(anchor, trajs, negat, ws);
  wt_kernel<<<2052, 256, 0, stream>>>(Wih, Whh, bih, bhh, ws);
  attn_kernel<<<4096, 256, 0, stream>>>(ws);

  // pick the largest xg chunk that fits the workspace
  size_t basebytes = XGBUF_OFF * sizeof(float);
  int CH = 0;
  const int cands[4] = {512, 256, 128, 64};
  for (int i = 0; i < 4; i++) {
    size_t need = basebytes + (size_t)cands[i] * 128 * 1024 * sizeof(float);
    if (need <= ws_size) { CH = cands[i]; break; }
  }
  if (CH) {
    int nch = TT / CH;
    int xgrid = 128 * ((CH >> 6) << 2);
    for (int c = 0; c < nch; c++) {
      int tc0 = c * CH;
      xg_kernel<<<xgrid, 256, 0, stream>>>(ws, tc0, CH, la, lt, ln);
      rec3_kernel<<<64, 1024, 0, stream>>>(ws, la, lt, ln, tc0, CH);
    }
  } else {
    rec_fb_kernel<<<64, 512, 0, stream>>>(ws, la, lt, ln);
  }
  finish_kernel<<<64, 256, 0, stream>>>(ws, W1, b1, W2, b2, W3, b3, out);
}

// Round 5
// 9156.299 us; speedup vs baseline: 1.8710x; 1.8710x over previous
//
#include <hip/hip_runtime.h>

constexpr int BB = 32;
constexpr int TT = 512;
constexpr size_t MSZ = (size_t)BB * TT * 128;              // one embedding array (floats)
constexpr size_t M_OFF = 0;                                // 3 * MSZ
constexpr size_t MASK_OFF = 3 * MSZ;                       // 3*B*T ints
constexpr size_t SUM_OFF = MASK_OFF + (size_t)3 * BB * TT; // 4 * MSZ
constexpr size_t WHH_OFF = SUM_OFF + 4 * MSZ;              // 256*1024 floats [k][hid][gate]
constexpr size_t WIH_OFF = WHH_OFF + (size_t)256 * 1024;   // 256*1024 floats [k][hid][gate]
constexpr size_t BIAS_OFF = WIH_OFF + (size_t)256 * 1024;  // 1024 floats [hid][gate]
constexpr size_t FSEL_OFF = BIAS_OFF + 1024;               // 128*256 floats [seq][hid]
constexpr size_t STATE_OFF = FSEL_OFF + (size_t)128 * 256; // h(32768) + c(32768), [hid][seq]
constexpr size_t HGLOB_OFF = STATE_OFF + 65536;            // 2 x [256 hid][128 seq]
constexpr size_t SYNC_OFF = HGLOB_OFF + 65536;             // 256 ints
constexpr size_t XGBUF_OFF = SYNC_OFF + 256;               // CH*128*1024 floats (chunked x-gates)

typedef float v2f __attribute__((ext_vector_type(2)));

__device__ __forceinline__ float sigm(float x) {
  return __builtin_amdgcn_rcpf(1.f + __builtin_amdgcn_exp2f(-1.44269504f * x));
}
__device__ __forceinline__ float tanhfast(float x) {
  float e = __builtin_amdgcn_exp2f(2.88539008f * x);
  return 1.f - 2.f * __builtin_amdgcn_rcpf(e + 1.f);
}
__device__ __forceinline__ float leaky(float x) { return x >= 0.f ? x : 0.1f * x; }

#define GLOAD_LDS16(gp, lp)                                                    \
  __builtin_amdgcn_global_load_lds(                                            \
      (const __attribute__((address_space(1))) void*)(gp),                     \
      (__attribute__((address_space(3))) void*)(lp), 16, 0, 0)

__global__ __launch_bounds__(256) void embed_kernel(
    const float* __restrict__ a, const float* __restrict__ t,
    const float* __restrict__ n, const float* __restrict__ Wm,
    const float* __restrict__ bm, float* __restrict__ ws) {
  int idx = blockIdx.x * 256 + threadIdx.x;   // < 3*B*T*128
  int h = idx & 127;
  int bt = idx >> 7;
  int traj = bt / (BB * TT);
  int r = bt - traj * (BB * TT);
  const float* src = traj == 0 ? a : (traj == 1 ? t : n);
  float x0 = src[r * 4 + 0], x1 = src[r * 4 + 1];
  float v = x0 * Wm[2 * h] + x1 * Wm[2 * h + 1] + bm[h];
  ws[M_OFF + (size_t)traj * MSZ + (size_t)r * 128 + h] = leaky(v);
}

__global__ __launch_bounds__(256) void mask_kernel(
    const float* __restrict__ a, const float* __restrict__ t,
    const float* __restrict__ n, float* __restrict__ ws) {
  int idx = blockIdx.x * 256 + threadIdx.x;   // < 3*B*T
  int traj = idx / (BB * TT);
  int r = idx - traj * (BB * TT);
  const float* src = traj == 0 ? a : (traj == 1 ? t : n);
  float gx = src[r * 4 + 2], gy = src[r * 4 + 3];
  ((int*)(ws + MASK_OFF))[idx] = (gy * 128.f + gx - 257.f) >= 0.5f ? 1 : 0;
}

// transpose Whh and Wih to [k][hid][gate] (torch gate order i,f,g,o); fold biases
__global__ __launch_bounds__(256) void wt_kernel(
    const float* __restrict__ Wih, const float* __restrict__ Whh,
    const float* __restrict__ bih, const float* __restrict__ bhh,
    float* __restrict__ ws) {
  int idx = blockIdx.x * 256 + threadIdx.x;  // < 525312
  if (idx < 262144) {
    int k = idx >> 10;
    int rest = idx & 1023;
    int hid = rest >> 2, g = rest & 3;
    ws[WHH_OFF + idx] = Whh[(g * 256 + hid) * 256 + k];
  } else if (idx < 524288) {
    int j = idx - 262144;
    int k = j >> 10;
    int rest = j & 1023;
    int hid = rest >> 2, g = rest & 3;
    ws[WIH_OFF + j] = Wih[(g * 256 + hid) * 256 + k];
  } else if (idx < 525312) {
    int j = idx - 524288;
    int hid = j >> 2, g = j & 3;
    ws[BIAS_OFF + j] = bih[g * 256 + hid] + bhh[g * 256 + hid];
  }
}

// one WG per (job, batch, 16-row t-tile); job 0..3 = L0..L3 source/dest pairs
__global__ __launch_bounds__(256) void attn_kernel(float* __restrict__ ws) {
  __shared__ float srcL[16][129];
  __shared__ float dtile[128][34];
  __shared__ float scoresL[16][514];
  __shared__ float rowscaleL[16];
  __shared__ int maskD[32];
  __shared__ int maskS[16];

  int tid = threadIdx.x;
  int job = blockIdx.x >> 10;
  int rem = blockIdx.x & 1023;
  int b = rem >> 5, ttile = rem & 31;
  int t0 = ttile * 16;
  int srcTr = (job == 1) ? 1 : ((job == 3) ? 2 : 0);
  int dstTr = (job == 0) ? 1 : ((job == 2) ? 2 : 0);
  const float* msrc = ws + M_OFF + (size_t)srcTr * MSZ + (size_t)b * TT * 128;
  const float* mdst = ws + M_OFF + (size_t)dstTr * MSZ + (size_t)b * TT * 128;
  const int* maskbase = (const int*)(ws + MASK_OFF);
  const int* smask = maskbase + srcTr * BB * TT + b * TT;
  const int* dmask = maskbase + dstTr * BB * TT + b * TT;
  float* out = ws + SUM_OFF + (size_t)job * MSZ + (size_t)b * TT * 128;

  for (int i = 0; i < 8; i++) {
    int idx = i * 256 + tid;
    int tr = idx >> 7, k = idx & 127;
    srcL[tr][k] = msrc[(size_t)(t0 + tr) * 128 + k];
  }
  if (tid < 16) maskS[tid] = smask[t0 + tid];
  __syncthreads();

  int s2 = tid & 15, trr = tid >> 4;
  for (int st = 0; st < 16; st++) {
    int s0 = st * 32;
    for (int i = 0; i < 16; i++) {
      int idx = i * 256 + tid;
      int s = idx >> 7, k = idx & 127;
      dtile[k][s] = mdst[(size_t)(s0 + s) * 128 + k];
    }
    if (tid < 32) maskD[tid] = dmask[s0 + tid];
    __syncthreads();
    float d0 = 0.f, d1 = 0.f;
#pragma unroll 8
    for (int k = 0; k < 128; k++) {
      float sv = srcL[trr][k];
      float2 dv = *(const float2*)&dtile[k][2 * s2];
      d0 += sv * dv.x;
      d1 += sv * dv.y;
    }
    scoresL[trr][s0 + 2 * s2]     = maskD[2 * s2]     ? d0 : -1e9f;
    scoresL[trr][s0 + 2 * s2 + 1] = maskD[2 * s2 + 1] ? d1 : -1e9f;
    __syncthreads();
  }

  {
    int r = tid >> 4, j = tid & 15;
    float mx = -3.0e38f;
    for (int i = 0; i < 32; i++) mx = fmaxf(mx, scoresL[r][j + 16 * i]);
    for (int m = 1; m < 16; m <<= 1) mx = fmaxf(mx, __shfl_xor(mx, m, 64));
    float den = 0.f;
    for (int i = 0; i < 32; i++) {
      float p = __builtin_amdgcn_exp2f((scoresL[r][j + 16 * i] - mx) * 1.44269504f);
      scoresL[r][j + 16 * i] = p;
      den += p;
    }
    for (int m = 1; m < 16; m <<= 1) den += __shfl_xor(den, m, 64);
    if (j == 0) rowscaleL[r] = (maskS[r] && mx > -5e8f) ? (1.f / den) : 0.f;
  }
  __syncthreads();

  int kk = tid & 127, tix = tid >> 7;
  float acc[8];
#pragma unroll
  for (int u = 0; u < 8; u++) acc[u] = 0.f;
  for (int st = 0; st < 16; st++) {
    int s0 = st * 32;
    for (int i = 0; i < 16; i++) {
      int idx = i * 256 + tid;
      int s = idx >> 7, k = idx & 127;
      dtile[k][s] = mdst[(size_t)(s0 + s) * 128 + k];
    }
    __syncthreads();
    for (int s = 0; s < 32; s += 2) {
      float2 dv = *(const float2*)&dtile[kk][s];
#pragma unroll
      for (int u = 0; u < 8; u++) {
        float2 p = *(const float2*)&scoresL[tix * 8 + u][s0 + s];
        acc[u] += p.x * dv.x + p.y * dv.y;
      }
    }
    __syncthreads();
  }
#pragma unroll
  for (int u = 0; u < 8; u++) {
    int tr = tix * 8 + u;
    out[(size_t)(t0 + tr) * 128 + kk] = acc[u] * rowscaleL[tr];
  }
}

// chunked x-gate GEMM: xg[seq][t-tc0][1024] = xcat @ WihT + bias for t in [tc0, tc0+CH)
__global__ __launch_bounds__(256) void xg_kernel(
    float* __restrict__ ws, int tc0, int CH,
    const int* __restrict__ la, const int* __restrict__ lt, const int* __restrict__ ln) {
  __shared__ float aT[32][68];
  __shared__ float bL[32][256];
  int tid = threadIdx.x;
  int bx = blockIdx.x;
  int tt4 = (CH >> 6) << 2;       // tiles*4 per seq
  int seq = bx / tt4;
  int rem = bx - seq * tt4;
  int tt = rem >> 2;
  int nc = rem & 3;
  int t0 = tc0 + tt * 64;
  int l = seq >> 5, b = seq & 31;
  const int* lens = (l == 1) ? lt : ((l == 3) ? ln : la);
  if (t0 >= lens[b]) return;      // beyond this sequence's length: dead work
  int srcTr = (l == 1) ? 1 : ((l == 3) ? 2 : 0);
  const float* xrow = ws + M_OFF + (size_t)srcTr * MSZ + (size_t)b * TT * 128;
  const float* srow = ws + SUM_OFF + (size_t)l * MSZ + (size_t)b * TT * 128;

  int r0 = tid >> 5;
  int c0 = (tid & 31) * 4;

  float acc[8][8];
#pragma unroll
  for (int i = 0; i < 8; i++)
#pragma unroll
    for (int j = 0; j < 8; j++) acc[i][j] = 0.f;

  for (int kc = 0; kc < 8; kc++) {
    int kbase = kc * 32;
    __syncthreads();
#pragma unroll
    for (int i = 0; i < 8; i++) {
      int idx = i * 256 + tid;
      int m = idx >> 5, kkv = idx & 31;
      float v;
      if (kbase < 128) {
        v = xrow[(size_t)(t0 + m) * 128 + kbase + kkv];
      } else {
        int k2 = kbase + kkv - 128;
        v = xrow[(size_t)(t0 + m) * 128 + k2] - srow[(size_t)(t0 + m) * 128 + k2];
      }
      aT[kkv][m] = v;
    }
#pragma unroll
    for (int i = 0; i < 32; i++) {
      int idx = i * 256 + tid;
      int kkv = idx >> 8, n = idx & 255;
      bL[kkv][n] = ws[WIH_OFF + (size_t)(kbase + kkv) * 1024 + nc * 256 + n];
    }
    __syncthreads();
#pragma unroll 2
    for (int kkv = 0; kkv < 32; kkv++) {
      float4 a0 = *(const float4*)&aT[kkv][r0 * 8];
      float4 a1 = *(const float4*)&aT[kkv][r0 * 8 + 4];
      float4 b0 = *(const float4*)&bL[kkv][c0];
      float4 b1 = *(const float4*)&bL[kkv][c0 + 128];
      float av[8] = {a0.x, a0.y, a0.z, a0.w, a1.x, a1.y, a1.z, a1.w};
      float bv[8] = {b0.x, b0.y, b0.z, b0.w, b1.x, b1.y, b1.z, b1.w};
#pragma unroll
      for (int i = 0; i < 8; i++)
#pragma unroll
        for (int j = 0; j < 8; j++) acc[i][j] += av[i] * bv[j];
    }
  }

  float4 bias0 = *(const float4*)&ws[BIAS_OFF + nc * 256 + c0];
  float4 bias1 = *(const float4*)&ws[BIAS_OFF + nc * 256 + c0 + 128];
#pragma unroll
  for (int i = 0; i < 8; i++) {
    int tl = t0 - tc0 + r0 * 8 + i;
    float* o = ws + XGBUF_OFF + ((size_t)seq * CH + tl) * 1024 + nc * 256 + c0;
    float4 v0 = {acc[i][0] + bias0.x, acc[i][1] + bias0.y,
                 acc[i][2] + bias0.z, acc[i][3] + bias0.w};
    float4 v1 = {acc[i][4] + bias1.x, acc[i][5] + bias1.y,
                 acc[i][6] + bias1.z, acc[i][7] + bias1.w};
    *(float4*)o = v0;
    *(float4*)(o + 128) = v1;
  }
}

// two-level device barrier: per-WG release flag; WG0 gathers then releases 'go'.
__device__ __forceinline__ void gsync(int* flags, int* go, int wg, int tid, int g) {
  __syncthreads();   // all prior LDS/global work in this WG done
  if (tid == 0)
    __hip_atomic_store(&flags[wg], g, __ATOMIC_RELEASE, __HIP_MEMORY_SCOPE_AGENT);
  if (wg == 0) {
    if (tid < 128) {
      while (__hip_atomic_load(&flags[tid], __ATOMIC_ACQUIRE, __HIP_MEMORY_SCOPE_AGENT) < g)
        __builtin_amdgcn_s_sleep(1);
    }
    __syncthreads();
    if (tid == 0)
      __hip_atomic_store(go, g, __ATOMIC_RELEASE, __HIP_MEMORY_SCOPE_AGENT);
  }
  if (tid == 0) {
    while (__hip_atomic_load(go, __ATOMIC_ACQUIRE, __HIP_MEMORY_SCOPE_AGENT) < g)
      __builtin_amdgcn_s_sleep(1);
  }
  __syncthreads();
}

// weight-stationary recurrence: 128 persistent WGs x 512 thr, grid barrier per step.
// WG j owns hids {2j, 2j+1}; thread holds its Whh slice (4 gates x 32 k) in VGPRs.
// h exchanged via global hgT[2][256 hid][128 seq]; staged to LDS by global_load_lds.
__global__ __launch_bounds__(512, 2) void rec4_kernel(
    float* __restrict__ ws, const int* __restrict__ la,
    const int* __restrict__ lt, const int* __restrict__ ln,
    int t0c, int CH, int gen0) {
  __shared__ float hT[256 * 128];     // [k][seq], 128 KiB
  __shared__ int lred[128];
  int tid = threadIdx.x;
  int wg = blockIdx.x;                // 0..127
  int ks = tid & 7;
  int hp = (tid >> 3) & 1;
  int slot = tid >> 4;                // 0..31
  int hid = wg * 2 + hp;
  int lane = tid & 63, wv = tid >> 6;
  int* flags = (int*)(ws + SYNC_OFF);
  int* go = flags + 192;

  // global max length (uniform across all WGs)
  int myl = 0;
  if (tid < 32) myl = la[tid];
  else if (tid < 64) myl = lt[tid - 32];
  else if (tid < 96) myl = ln[tid - 64];
  if (tid < 128) lred[tid] = myl;
  __syncthreads();
  for (int s = 64; s > 0; s >>= 1) {
    if (tid < s) lred[tid] = max(lred[tid], lred[tid + s]);
    __syncthreads();
  }
  int gmax = lred[0];
  int tendg = min(CH, gmax - t0c);
  if (tendg <= 0) return;

  // persistent weights: w[k][hid][gate], k = ks + 8*kk
  v2f wif[32], wgo[32];
  {
    const float* wsrc = ws + WHH_OFF + hid * 4;
#pragma unroll
    for (int kk = 0; kk < 32; kk++) {
      float4 w = *(const float4*)(wsrc + (size_t)(ks + kk * 8) * 1024);
      wif[kk] = (v2f){w.x, w.y};
      wgo[kk] = (v2f){w.z, w.w};
    }
  }

  int seqidx = slot * 4 + (ks & 3);   // owned seq for ks<4 lanes
  int larr = seqidx >> 5, lb = seqidx & 31;
  int mylen = (larr == 1) ? lt[lb] : ((larr == 3) ? ln[lb] : la[lb]);
  float c_st = 0.f, hlast = 0.f;
  if (t0c > 0 && ks < 4) {
    hlast = ws[STATE_OFF + (size_t)hid * 128 + seqidx];
    c_st = ws[STATE_OFF + 32768 + (size_t)hid * 128 + seqidx];
  }
  float* hg0 = ws + HGLOB_OFF;
  float* hg1 = hg0 + 32768;
  if (ks < 4) hg0[(size_t)hid * 128 + seqidx] = hlast;   // init "prev" buffer
  const float* xgb = ws + XGBUF_OFF + hid * 4;
  gsync(flags, go, wg, tid, gen0);

  int pb = 0;
  for (int tl = 0; tl < tendg; tl++) {
    const float* hsrc = pb ? hg1 : hg0;
    float* hdst = pb ? hg0 : hg1;
    // stage hsrc (32768 floats) -> LDS, contiguous async copies
#pragma unroll
    for (int j = 0; j < 16; j++) {
      int fb = (j * 8 + wv) * 256;
      GLOAD_LDS16(hsrc + fb + lane * 4, &hT[fb]);
    }
    __syncthreads();

    v2f aif[4] = {{0,0},{0,0},{0,0},{0,0}};
    v2f ago[4] = {{0,0},{0,0},{0,0},{0,0}};
#pragma unroll
    for (int kk = 0; kk < 32; kk++) {
      int k = ks + kk * 8;
      float4 h4 = *(const float4*)&hT[k * 128 + slot * 4];
      v2f wi = wif[kk], wo = wgo[kk];
      aif[0] += wi * (v2f){h4.x, h4.x}; ago[0] += wo * (v2f){h4.x, h4.x};
      aif[1] += wi * (v2f){h4.y, h4.y}; ago[1] += wo * (v2f){h4.y, h4.y};
      aif[2] += wi * (v2f){h4.z, h4.z}; ago[2] += wo * (v2f){h4.z, h4.z};
      aif[3] += wi * (v2f){h4.w, h4.w}; ago[3] += wo * (v2f){h4.w, h4.w};
    }
    // reduce over the 8 k-slices (lane bits 0..2)
#pragma unroll
    for (int u = 0; u < 4; u++) {
#pragma unroll
      for (int m = 1; m <= 4; m <<= 1) {
        aif[u].x += __shfl_xor(aif[u].x, m, 64);
        aif[u].y += __shfl_xor(aif[u].y, m, 64);
        ago[u].x += __shfl_xor(ago[u].x, m, 64);
        ago[u].y += __shfl_xor(ago[u].y, m, 64);
      }
    }
    if (ks < 4) {
      v2f a_if = ks == 0 ? aif[0] : ks == 1 ? aif[1] : ks == 2 ? aif[2] : aif[3];
      v2f a_go = ks == 0 ? ago[0] : ks == 1 ? ago[1] : ks == 2 ? ago[2] : ago[3];
      float4 xgv = *(const float4*)(xgb + ((size_t)seqidx * CH + tl) * 1024);
      float gi = a_if.x + xgv.x, gf = a_if.y + xgv.y;
      float gg = a_go.x + xgv.z, go_ = a_go.y + xgv.w;
      c_st = sigm(gf) * c_st + sigm(gi) * tanhfast(gg);
      float h = sigm(go_) * tanhfast(c_st);
      hlast = h;
      hdst[(size_t)hid * 128 + seqidx] = h;
      int t = t0c + tl;
      if (t == mylen - 1) ws[FSEL_OFF + (size_t)seqidx * 256 + hid] = h;
    }
    if (tl + 1 < tendg) gsync(flags, go, wg, tid, gen0 + 1 + tl);
    pb ^= 1;
  }
  if (ks < 4) {
    ws[STATE_OFF + (size_t)hid * 128 + seqidx] = hlast;
    ws[STATE_OFF + 32768 + (size_t)hid * 128 + seqidx] = c_st;
  }
}

// fallback if ws too small for chunked xg: streams Wih+Whh per step (K=512)
__global__ __launch_bounds__(512, 2) void rec_fb_kernel(
    float* __restrict__ ws, const int* __restrict__ la,
    const int* __restrict__ lt, const int* __restrict__ ln) {
  __shared__ float hL[2][256];
  __shared__ float xL[2][256];
  int tid = threadIdx.x;
  int sl = tid >> 8;
  int hid = tid & 255;
  int seq = blockIdx.x * 2 + sl;
  int l = seq >> 5, b = seq & 31;
  int srcTr = (l == 1) ? 1 : ((l == 3) ? 2 : 0);
  const float* xrow = ws + M_OFF + (size_t)srcTr * MSZ + (size_t)b * TT * 128;
  const float* srow = ws + SUM_OFF + (size_t)l * MSZ + (size_t)b * TT * 128;
  const int* lens = (l == 1) ? lt : ((l == 3) ? ln : la);
  int mylen = lens[b];
  const float* wh = ws + WHH_OFF + (hid << 2);
  const float* wi = ws + WIH_OFF + (hid << 2);
  float4 biasv = *(const float4*)&ws[BIAS_OFF + (hid << 2)];
  float c = 0.f;
  hL[sl][hid] = 0.f;
  xL[sl][hid] = hid < 128 ? xrow[hid] : xrow[hid - 128] - srow[hid - 128];
  __syncthreads();
  float* fout = ws + FSEL_OFF + (size_t)seq * 256;

  for (int t = 0; t < TT; t++) {
    float gi = biasv.x, gf = biasv.y, gg = biasv.z, go = biasv.w;
    {
      const float* hp = &hL[sl][0];
#pragma unroll 4
      for (int k = 0; k < 256; k += 4) {
        float4 hv = *(const float4*)(hp + k);
        const float* w = wh + (size_t)k * 1024;
        float4 w0 = *(const float4*)(w);
        float4 w1 = *(const float4*)(w + 1024);
        float4 w2 = *(const float4*)(w + 2048);
        float4 w3 = *(const float4*)(w + 3072);
        gi += hv.x * w0.x + hv.y * w1.x + hv.z * w2.x + hv.w * w3.x;
        gf += hv.x * w0.y + hv.y * w1.y + hv.z * w2.y + hv.w * w3.y;
        gg += hv.x * w0.z + hv.y * w1.z + hv.z * w2.z + hv.w * w3.z;
        go += hv.x * w0.w + hv.y * w1.w + hv.z * w2.w + hv.w * w3.w;
      }
    }
    {
      const float* xp = &xL[sl][0];
#pragma unroll 4
      for (int k = 0; k < 256; k += 4) {
        float4 xv = *(const float4*)(xp + k);
        const float* w = wi + (size_t)k * 1024;
        float4 w0 = *(const float4*)(w);
        float4 w1 = *(const float4*)(w + 1024);
        float4 w2 = *(const float4*)(w + 2048);
        float4 w3 = *(const float4*)(w + 3072);
        gi += xv.x * w0.x + xv.y * w1.x + xv.z * w2.x + xv.w * w3.x;
        gf += xv.x * w0.y + xv.y * w1.y + xv.z * w2.y + xv.w * w3.y;
        gg += xv.x * w0.z + xv.y * w1.z + xv.z * w2.z + xv.w * w3.z;
        go += xv.x * w0.w + xv.y * w1.w + xv.z * w2.w + xv.w * w3.w;
      }
    }
    float c_new = sigm(gf) * c + sigm(gi) * tanhfast(gg);
    c = c_new;
    float h = sigm(go) * tanhfast(c_new);
    __syncthreads();
    hL[sl][hid] = h;
    if (t + 1 < TT) {
      int tn = t + 1;
      xL[sl][hid] = hid < 128 ? xrow[tn * 128 + hid]
                              : xrow[tn * 128 + hid - 128] - srow[tn * 128 + hid - 128];
    }
    if (t == mylen - 1) fout[hid] = h;
    __syncthreads();
  }
}

__global__ __launch_bounds__(256) void finish_kernel(
    const float* __restrict__ ws, const float* __restrict__ W1,
    const float* __restrict__ b1, const float* __restrict__ W2,
    const float* __restrict__ b2, const float* __restrict__ W3,
    const float* __restrict__ b3, float* __restrict__ out) {
  __shared__ float oL[256];
  __shared__ float wsum[4];
  int tid = threadIdx.x;
  int p = blockIdx.x >> 5, b = blockIdx.x & 31;
  const float* fa = ws + FSEL_OFF + (size_t)((2 * p) * 32 + b) * 256;
  const float* fb = ws + FSEL_OFF + (size_t)((2 * p + 1) * 32 + b) * 256;
  oL[tid] = fa[tid];
  __syncthreads();
  float a1 = b1[tid], a2 = b2[tid], a3 = b3[tid];
  const float* w1r = W1 + tid * 256;
  const float* w2r = W2 + tid * 256;
  const float* w3r = W3 + tid * 256;
  for (int k = 0; k < 256; k++) {
    float ov = oL[k];
    a1 += ov * w1r[k];
    a2 += ov * w2r[k];
    a3 += ov * w3r[k];
  }
  float cg = sigm(a1) * leaky(a2);
  float res = oL[tid] + sigm(a3) * leaky(cg);
  float d = res - fb[tid] + 1e-6f;
  float sq = d * d;
  for (int m = 32; m >= 1; m >>= 1) sq += __shfl_down(sq, m, 64);
  if ((tid & 63) == 0) wsum[tid >> 6] = sq;
  __syncthreads();
  if (tid == 0) {
    float s = wsum[0] + wsum[1] + wsum[2] + wsum[3];
    out[p * BB + b] = expf(sqrtf(s));
  }
}

extern "C" void kernel_launch(void* const* d_in, const int* in_sizes, int n_in,
                              void* d_out, int out_size, void* d_ws, size_t ws_size,
                              hipStream_t stream) {
  const float* anchor = (const float*)d_in[0];
  const float* trajs = (const float*)d_in[1];
  const float* negat = (const float*)d_in[2];
  const int* la = (const int*)d_in[3];
  const int* lt = (const int*)d_in[4];
  const int* ln = (const int*)d_in[5];
  const float* Wm = (const float*)d_in[6];
  const float* bm = (const float*)d_in[7];
  const float* Wih = (const float*)d_in[8];
  const float* Whh = (const float*)d_in[9];
  const float* bih = (const float*)d_in[10];
  const float* bhh = (const float*)d_in[11];
  const float* W1 = (const float*)d_in[12];
  const float* b1 = (const float*)d_in[13];
  const float* W2 = (const float*)d_in[14];
  const float* b2 = (const float*)d_in[15];
  const float* W3 = (const float*)d_in[16];
  const float* b3 = (const float*)d_in[17];
  float* ws = (float*)d_ws;
  float* out = (float*)d_out;

  // zero the barrier flags (ws is re-poisoned before every call)
  hipMemsetAsync((char*)d_ws + SYNC_OFF * sizeof(float), 0, 1024, stream);

  embed_kernel<<<(3 * BB * TT * 128) / 256, 256, 0, stream>>>(anchor, trajs, negat, Wm, bm, ws);
  mask_kernel<<<(3 * BB * TT) / 256, 256, 0, stream>>>(anchor, trajs, negat, ws);
  wt_kernel<<<2052, 256, 0, stream>>>(Wih, Whh, bih, bhh, ws);
  attn_kernel<<<4096, 256, 0, stream>>>(ws);

  // pick the largest xg chunk that fits the workspace
  size_t basebytes = XGBUF_OFF * sizeof(float);
  int CH = 0;
  const int cands[4] = {512, 256, 128, 64};
  for (int i = 0; i < 4; i++) {
    size_t need = basebytes + (size_t)cands[i] * 128 * 1024 * sizeof(float);
    if (need <= ws_size) { CH = cands[i]; break; }
  }
  if (CH) {
    int nch = TT / CH;
    int xgrid = 128 * ((CH >> 6) << 2);
    for (int c = 0; c < nch; c++) {
      int tc0 = c * CH;
      xg_kernel<<<xgrid, 256, 0, stream>>>(ws, tc0, CH, la, lt, ln);
      rec4_kernel<<<128, 512, 0, stream>>>(ws, la, lt, ln, tc0, CH, 1 + c * (CH + 1));
    }
  } else {
    rec_fb_kernel<<<64, 512, 0, stream>>>(ws, la, lt, ln);
  }
  finish_kernel<<<64, 256, 0, stream>>>(ws, W1, b1, W2, b2, W3, b3, out);
}

// Round 6
// 2379.570 us; speedup vs baseline: 7.1992x; 3.8479x over previous
//
#include <hip/hip_runtime.h>

constexpr int BB = 32;
constexpr int TT = 512;
constexpr size_t MSZ = (size_t)BB * TT * 128;              // one embedding array (floats)
constexpr size_t M_OFF = 0;                                // 3 * MSZ
constexpr size_t MASK_OFF = 3 * MSZ;                       // 3*B*T ints
constexpr size_t SUM_OFF = MASK_OFF + (size_t)3 * BB * TT; // 4 * MSZ
constexpr size_t WHH_OFF = SUM_OFF + 4 * MSZ;              // 256*1024 floats [k][hid][gate]
constexpr size_t WIH_OFF = WHH_OFF + (size_t)256 * 1024;   // 256*1024 floats [k][hid][gate]
constexpr size_t BIAS_OFF = WIH_OFF + (size_t)256 * 1024;  // 1024 floats [hid][gate]
constexpr size_t W5_OFF = BIAS_OFF + 1024;                 // 131072 dwords fp16x2 Whh, per-thread order
constexpr size_t FSEL_OFF = W5_OFF + 131072;               // 128*256 floats [seq][hid]
constexpr size_t STATE_OFF = FSEL_OFF + (size_t)128 * 256; // h(32768) + c(32768) f32
constexpr size_t XGBUF_OFF = STATE_OFF + 65536;            // CH*128*1024 floats (chunked x-gates)

typedef _Float16 h2v __attribute__((ext_vector_type(2)));

__device__ __forceinline__ float sigm(float x) {
  return __builtin_amdgcn_rcpf(1.f + __builtin_amdgcn_exp2f(-1.44269504f * x));
}
__device__ __forceinline__ float tanhfast(float x) {
  float e = __builtin_amdgcn_exp2f(2.88539008f * x);
  return 1.f - 2.f * __builtin_amdgcn_rcpf(e + 1.f);
}
__device__ __forceinline__ float leaky(float x) { return x >= 0.f ? x : 0.1f * x; }

__device__ __forceinline__ unsigned int pack2h(float a, float b) {
  h2v h;
  h.x = (_Float16)a;   // RNE v_cvt_f16_f32
  h.y = (_Float16)b;
  return __builtin_bit_cast(unsigned int, h);
}

__device__ __forceinline__ float fdot2u(unsigned int a, unsigned int b, float c) {
#if __has_builtin(__builtin_amdgcn_fdot2)
  return __builtin_amdgcn_fdot2(__builtin_bit_cast(h2v, a), __builtin_bit_cast(h2v, b), c, false);
#else
  h2v ha = __builtin_bit_cast(h2v, a), hb = __builtin_bit_cast(h2v, b);
  return c + (float)ha.x * (float)hb.x + (float)ha.y * (float)hb.y;
#endif
}

#define GLOAD_LDS16(gp, lp)                                                    \
  __builtin_amdgcn_global_load_lds(                                            \
      (const __attribute__((address_space(1))) void*)(gp),                     \
      (__attribute__((address_space(3))) void*)(lp), 16, 0, 0)

__global__ __launch_bounds__(256) void embed_kernel(
    const float* __restrict__ a, const float* __restrict__ t,
    const float* __restrict__ n, const float* __restrict__ Wm,
    const float* __restrict__ bm, float* __restrict__ ws) {
  int idx = blockIdx.x * 256 + threadIdx.x;   // < 3*B*T*128
  int h = idx & 127;
  int bt = idx >> 7;
  int traj = bt / (BB * TT);
  int r = bt - traj * (BB * TT);
  const float* src = traj == 0 ? a : (traj == 1 ? t : n);
  float x0 = src[r * 4 + 0], x1 = src[r * 4 + 1];
  float v = x0 * Wm[2 * h] + x1 * Wm[2 * h + 1] + bm[h];
  ws[M_OFF + (size_t)traj * MSZ + (size_t)r * 128 + h] = leaky(v);
}

__global__ __launch_bounds__(256) void mask_kernel(
    const float* __restrict__ a, const float* __restrict__ t,
    const float* __restrict__ n, float* __restrict__ ws) {
  int idx = blockIdx.x * 256 + threadIdx.x;   // < 3*B*T
  int traj = idx / (BB * TT);
  int r = idx - traj * (BB * TT);
  const float* src = traj == 0 ? a : (traj == 1 ? t : n);
  float gx = src[r * 4 + 2], gy = src[r * 4 + 3];
  ((int*)(ws + MASK_OFF))[idx] = (gy * 128.f + gx - 257.f) >= 0.5f ? 1 : 0;
}

// transpose Whh/Wih to [k][hid][gate]; fold biases; emit packed-fp16 W5 for rec5
__global__ __launch_bounds__(256) void wt_kernel(
    const float* __restrict__ Wih, const float* __restrict__ Whh,
    const float* __restrict__ bih, const float* __restrict__ bhh,
    float* __restrict__ ws) {
  int idx = blockIdx.x * 256 + threadIdx.x;  // < 656384
  if (idx < 262144) {
    int k = idx >> 10;
    int rest = idx & 1023;
    int hid = rest >> 2, g = rest & 3;
    ws[WHH_OFF + idx] = Whh[(g * 256 + hid) * 256 + k];
  } else if (idx < 524288) {
    int j = idx - 262144;
    int k = j >> 10;
    int rest = j & 1023;
    int hid = rest >> 2, g = rest & 3;
    ws[WIH_OFF + j] = Wih[(g * 256 + hid) * 256 + k];
  } else if (idx < 525312) {
    int j = idx - 524288;
    int hid = j >> 2, g = j & 3;
    ws[BIAS_OFF + j] = bih[g * 256 + hid] + bhh[g * 256 + hid];
  } else if (idx < 656384) {
    // W5[kh][gate][g][hid][u] = pack(Whh[gate*256+hid][k0], [k0+1]), k0=kh*128+g*8+u*2
    int j = idx - 525312;
    int u = j & 3;
    int hid = (j >> 2) & 255;
    int g = (j >> 10) & 15;
    int gate = (j >> 14) & 3;
    int kh = j >> 16;
    int k0 = kh * 128 + g * 8 + u * 2;
    const float* row = Whh + (size_t)(gate * 256 + hid) * 256;
    ((unsigned int*)ws)[W5_OFF + j] = pack2h(row[k0], row[k0 + 1]);
  }
}

// one WG per (job, batch, 16-row t-tile); job 0..3 = L0..L3 source/dest pairs
__global__ __launch_bounds__(256) void attn_kernel(float* __restrict__ ws) {
  __shared__ float srcL[16][129];
  __shared__ float dtile[128][34];
  __shared__ float scoresL[16][514];
  __shared__ float rowscaleL[16];
  __shared__ int maskD[32];
  __shared__ int maskS[16];

  int tid = threadIdx.x;
  int job = blockIdx.x >> 10;
  int rem = blockIdx.x & 1023;
  int b = rem >> 5, ttile = rem & 31;
  int t0 = ttile * 16;
  int srcTr = (job == 1) ? 1 : ((job == 3) ? 2 : 0);
  int dstTr = (job == 0) ? 1 : ((job == 2) ? 2 : 0);
  const float* msrc = ws + M_OFF + (size_t)srcTr * MSZ + (size_t)b * TT * 128;
  const float* mdst = ws + M_OFF + (size_t)dstTr * MSZ + (size_t)b * TT * 128;
  const int* maskbase = (const int*)(ws + MASK_OFF);
  const int* smask = maskbase + srcTr * BB * TT + b * TT;
  const int* dmask = maskbase + dstTr * BB * TT + b * TT;
  float* out = ws + SUM_OFF + (size_t)job * MSZ + (size_t)b * TT * 128;

  for (int i = 0; i < 8; i++) {
    int idx = i * 256 + tid;
    int tr = idx >> 7, k = idx & 127;
    srcL[tr][k] = msrc[(size_t)(t0 + tr) * 128 + k];
  }
  if (tid < 16) maskS[tid] = smask[t0 + tid];
  __syncthreads();

  int s2 = tid & 15, trr = tid >> 4;
  for (int st = 0; st < 16; st++) {
    int s0 = st * 32;
    for (int i = 0; i < 16; i++) {
      int idx = i * 256 + tid;
      int s = idx >> 7, k = idx & 127;
      dtile[k][s] = mdst[(size_t)(s0 + s) * 128 + k];
    }
    if (tid < 32) maskD[tid] = dmask[s0 + tid];
    __syncthreads();
    float d0 = 0.f, d1 = 0.f;
#pragma unroll 8
    for (int k = 0; k < 128; k++) {
      float sv = srcL[trr][k];
      float2 dv = *(const float2*)&dtile[k][2 * s2];
      d0 += sv * dv.x;
      d1 += sv * dv.y;
    }
    scoresL[trr][s0 + 2 * s2]     = maskD[2 * s2]     ? d0 : -1e9f;
    scoresL[trr][s0 + 2 * s2 + 1] = maskD[2 * s2 + 1] ? d1 : -1e9f;
    __syncthreads();
  }

  {
    int r = tid >> 4, j = tid & 15;
    float mx = -3.0e38f;
    for (int i = 0; i < 32; i++) mx = fmaxf(mx, scoresL[r][j + 16 * i]);
    for (int m = 1; m < 16; m <<= 1) mx = fmaxf(mx, __shfl_xor(mx, m, 64));
    float den = 0.f;
    for (int i = 0; i < 32; i++) {
      float p = __builtin_amdgcn_exp2f((scoresL[r][j + 16 * i] - mx) * 1.44269504f);
      scoresL[r][j + 16 * i] = p;
      den += p;
    }
    for (int m = 1; m < 16; m <<= 1) den += __shfl_xor(den, m, 64);
    if (j == 0) rowscaleL[r] = (maskS[r] && mx > -5e8f) ? (1.f / den) : 0.f;
  }
  __syncthreads();

  int kk = tid & 127, tix = tid >> 7;
  float acc[8];
#pragma unroll
  for (int u = 0; u < 8; u++) acc[u] = 0.f;
  for (int st = 0; st < 16; st++) {
    int s0 = st * 32;
    for (int i = 0; i < 16; i++) {
      int idx = i * 256 + tid;
      int s = idx >> 7, k = idx & 127;
      dtile[k][s] = mdst[(size_t)(s0 + s) * 128 + k];
    }
    __syncthreads();
    for (int s = 0; s < 32; s += 2) {
      float2 dv = *(const float2*)&dtile[kk][s];
#pragma unroll
      for (int u = 0; u < 8; u++) {
        float2 p = *(const float2*)&scoresL[tix * 8 + u][s0 + s];
        acc[u] += p.x * dv.x + p.y * dv.y;
      }
    }
    __syncthreads();
  }
#pragma unroll
  for (int u = 0; u < 8; u++) {
    int tr = tix * 8 + u;
    out[(size_t)(t0 + tr) * 128 + kk] = acc[u] * rowscaleL[tr];
  }
}

// chunked x-gate GEMM: xg[seq][t-tc0][1024] = xcat @ WihT + bias (fp32)
__global__ __launch_bounds__(256) void xg_kernel(
    float* __restrict__ ws, int tc0, int CH,
    const int* __restrict__ la, const int* __restrict__ lt, const int* __restrict__ ln) {
  __shared__ float aT[32][68];
  __shared__ float bL[32][256];
  int tid = threadIdx.x;
  int bx = blockIdx.x;
  int tt4 = (CH >> 6) << 2;       // tiles*4 per seq
  int seq = bx / tt4;
  int rem = bx - seq * tt4;
  int tt = rem >> 2;
  int nc = rem & 3;
  int t0 = tc0 + tt * 64;
  int l = seq >> 5, b = seq & 31;
  const int* lens = (l == 1) ? lt : ((l == 3) ? ln : la);
  if (t0 >= lens[b]) return;      // beyond this sequence's length: dead work
  int srcTr = (l == 1) ? 1 : ((l == 3) ? 2 : 0);
  const float* xrow = ws + M_OFF + (size_t)srcTr * MSZ + (size_t)b * TT * 128;
  const float* srow = ws + SUM_OFF + (size_t)l * MSZ + (size_t)b * TT * 128;

  int r0 = tid >> 5;
  int c0 = (tid & 31) * 4;

  float acc[8][8];
#pragma unroll
  for (int i = 0; i < 8; i++)
#pragma unroll
    for (int j = 0; j < 8; j++) acc[i][j] = 0.f;

  for (int kc = 0; kc < 8; kc++) {
    int kbase = kc * 32;
    __syncthreads();
#pragma unroll
    for (int i = 0; i < 8; i++) {
      int idx = i * 256 + tid;
      int m = idx >> 5, kkv = idx & 31;
      float v;
      if (kbase < 128) {
        v = xrow[(size_t)(t0 + m) * 128 + kbase + kkv];
      } else {
        int k2 = kbase + kkv - 128;
        v = xrow[(size_t)(t0 + m) * 128 + k2] - srow[(size_t)(t0 + m) * 128 + k2];
      }
      aT[kkv][m] = v;
    }
#pragma unroll
    for (int i = 0; i < 32; i++) {
      int idx = i * 256 + tid;
      int kkv = idx >> 8, n = idx & 255;
      bL[kkv][n] = ws[WIH_OFF + (size_t)(kbase + kkv) * 1024 + nc * 256 + n];
    }
    __syncthreads();
#pragma unroll 2
    for (int kkv = 0; kkv < 32; kkv++) {
      float4 a0 = *(const float4*)&aT[kkv][r0 * 8];
      float4 a1 = *(const float4*)&aT[kkv][r0 * 8 + 4];
      float4 b0 = *(const float4*)&bL[kkv][c0];
      float4 b1 = *(const float4*)&bL[kkv][c0 + 128];
      float av[8] = {a0.x, a0.y, a0.z, a0.w, a1.x, a1.y, a1.z, a1.w};
      float bv[8] = {b0.x, b0.y, b0.z, b0.w, b1.x, b1.y, b1.z, b1.w};
#pragma unroll
      for (int i = 0; i < 8; i++)
#pragma unroll
        for (int j = 0; j < 8; j++) acc[i][j] += av[i] * bv[j];
    }
  }

  float4 bias0 = *(const float4*)&ws[BIAS_OFF + nc * 256 + c0];
  float4 bias1 = *(const float4*)&ws[BIAS_OFF + nc * 256 + c0 + 128];
#pragma unroll
  for (int i = 0; i < 8; i++) {
    int tl = t0 - tc0 + r0 * 8 + i;
    float* o = ws + XGBUF_OFF + ((size_t)seq * CH + tl) * 1024 + nc * 256 + c0;
    float4 v0 = {acc[i][0] + bias0.x, acc[i][1] + bias0.y,
                 acc[i][2] + bias0.z, acc[i][3] + bias0.w};
    float4 v1 = {acc[i][4] + bias1.x, acc[i][5] + bias1.y,
                 acc[i][6] + bias1.z, acc[i][7] + bias1.w};
    *(float4*)o = v0;
    *(float4*)(o + 128) = v1;
  }
}

// CU-resident recurrence: 128 WGs x 512 thr, 1 seq/WG, NO cross-WG traffic.
// thread = (hid, kh). fp16 Whh: gates i,f,g in VGPRs (192 dw), gate o in LDS (128KB).
// h as fp16 pairs in LDS (512B, broadcast reads); f32 c-state; fdot2 MACs.
__global__ __launch_bounds__(512, 2) void rec5_kernel(
    float* __restrict__ ws, const int* __restrict__ la,
    const int* __restrict__ lt, const int* __restrict__ ln,
    int t0c, int CH) {
  __shared__ unsigned int o_w[32768];   // [kh][g][hid][u] 16B units -> 128KB
  __shared__ unsigned int hp[128];      // h as fp16x2, pair p = (h[2p],h[2p+1])
  __shared__ float4 part[256];          // kh=1 partial gate sums
  int tid = threadIdx.x;
  int hid = tid & 255;
  int kh = tid >> 8;
  int seq = blockIdx.x;
  int l = seq >> 5, b = seq & 31;
  int mylen = (l == 1) ? lt[b] : ((l == 3) ? ln[b] : la[b]);
  int tend = min(CH, mylen - t0c);
  if (tend <= 0) return;

  const unsigned int* W5 = (const unsigned int*)ws + W5_OFF;

  // VGPR-resident weights, gates i,f,g (48 coalesced b128 loads)
  uint4 wi[16], wf[16], wg[16];
  {
    const unsigned int* base = W5 + (size_t)kh * 65536 + hid * 4;
#pragma unroll
    for (int g = 0; g < 16; g++) {
      wi[g] = *(const uint4*)(base + (0 * 16 + g) * 1024);
      wf[g] = *(const uint4*)(base + (1 * 16 + g) * 1024);
      wg[g] = *(const uint4*)(base + (2 * 16 + g) * 1024);
    }
  }
  // gate o -> LDS via global_load_lds (per wave: 16 x 1KB slices)
  {
    int wv = tid >> 6;
    int khw = wv >> 2;
    int hidbase = (wv & 3) * 64;
    const unsigned int* srcb = W5 + (size_t)(khw * 4 + 3) * 16384 + (hidbase + (tid & 63)) * 4;
#pragma unroll
    for (int g = 0; g < 16; g++) {
      GLOAD_LDS16(srcb + g * 1024, &o_w[((khw * 16 + g) * 256 + hidbase) * 4]);
    }
  }

  // init / restore state
  float c_st = 0.f, hlast = 0.f;
  if (t0c == 0) {
    if (tid < 128) hp[tid] = 0u;
  } else {
    if (tid < 128) {
      float h0 = ws[STATE_OFF + (size_t)seq * 256 + 2 * tid];
      float h1 = ws[STATE_OFF + (size_t)seq * 256 + 2 * tid + 1];
      hp[tid] = pack2h(h0, h1);
    }
    if (kh == 0) {
      hlast = ws[STATE_OFF + (size_t)seq * 256 + hid];
      c_st = ws[STATE_OFF + 32768 + (size_t)seq * 256 + hid];
    }
  }
  const float* xgrow = ws + XGBUF_OFF + ((size_t)seq * CH) * 1024 + hid * 4;
  float* fout = ws + FSEL_OFF + (size_t)seq * 256;
  __syncthreads();

  for (int tl = 0; tl < tend; tl++) {
    float ai = 0.f, af = 0.f, ag = 0.f, ao = 0.f;
    const unsigned int* hb = &hp[kh * 64];
#pragma unroll
    for (int g = 0; g < 16; g++) {
      uint4 h4 = *(const uint4*)(hb + g * 4);                       // wave-uniform broadcast
      uint4 o4 = *(const uint4*)&o_w[((kh * 16 + g) * 256 + hid) * 4];  // coalesced 16B/lane
      ai = fdot2u(wi[g].x, h4.x, ai); ai = fdot2u(wi[g].y, h4.y, ai);
      ai = fdot2u(wi[g].z, h4.z, ai); ai = fdot2u(wi[g].w, h4.w, ai);
      af = fdot2u(wf[g].x, h4.x, af); af = fdot2u(wf[g].y, h4.y, af);
      af = fdot2u(wf[g].z, h4.z, af); af = fdot2u(wf[g].w, h4.w, af);
      ag = fdot2u(wg[g].x, h4.x, ag); ag = fdot2u(wg[g].y, h4.y, ag);
      ag = fdot2u(wg[g].z, h4.z, ag); ag = fdot2u(wg[g].w, h4.w, ag);
      ao = fdot2u(o4.x, h4.x, ao); ao = fdot2u(o4.y, h4.y, ao);
      ao = fdot2u(o4.z, h4.z, ao); ao = fdot2u(o4.w, h4.w, ao);
    }
    if (kh == 1) part[hid] = make_float4(ai, af, ag, ao);
    __syncthreads();
    if (kh == 0) {
      float4 p2 = part[hid];
      float4 xv = *(const float4*)(xgrow + (size_t)tl * 1024);
      float gi = ai + p2.x + xv.x;
      float gf = af + p2.y + xv.y;
      float gg = ag + p2.z + xv.z;
      float go_ = ao + p2.w + xv.w;
      c_st = sigm(gf) * c_st + sigm(gi) * tanhfast(gg);
      float h = sigm(go_) * tanhfast(c_st);
      hlast = h;
      ((_Float16*)hp)[hid] = (_Float16)h;
      if (t0c + tl == mylen - 1) fout[hid] = h;
    }
    __syncthreads();
  }
  if (kh == 0) {
    ws[STATE_OFF + (size_t)seq * 256 + hid] = hlast;
    ws[STATE_OFF + 32768 + (size_t)seq * 256 + hid] = c_st;
  }
}

// fallback if ws too small for chunked xg: streams Wih+Whh per step (K=512)
__global__ __launch_bounds__(512, 2) void rec_fb_kernel(
    float* __restrict__ ws, const int* __restrict__ la,
    const int* __restrict__ lt, const int* __restrict__ ln) {
  __shared__ float hL[2][256];
  __shared__ float xL[2][256];
  int tid = threadIdx.x;
  int sl = tid >> 8;
  int hid = tid & 255;
  int seq = blockIdx.x * 2 + sl;
  int l = seq >> 5, b = seq & 31;
  int srcTr = (l == 1) ? 1 : ((l == 3) ? 2 : 0);
  const float* xrow = ws + M_OFF + (size_t)srcTr * MSZ + (size_t)b * TT * 128;
  const float* srow = ws + SUM_OFF + (size_t)l * MSZ + (size_t)b * TT * 128;
  const int* lens = (l == 1) ? lt : ((l == 3) ? ln : la);
  int mylen = lens[b];
  const float* wh = ws + WHH_OFF + (hid << 2);
  const float* wi = ws + WIH_OFF + (hid << 2);
  float4 biasv = *(const float4*)&ws[BIAS_OFF + (hid << 2)];
  float c = 0.f;
  hL[sl][hid] = 0.f;
  xL[sl][hid] = hid < 128 ? xrow[hid] : xrow[hid - 128] - srow[hid - 128];
  __syncthreads();
  float* fout = ws + FSEL_OFF + (size_t)seq * 256;

  for (int t = 0; t < TT; t++) {
    float gi = biasv.x, gf = biasv.y, gg = biasv.z, go = biasv.w;
    {
      const float* hp = &hL[sl][0];
#pragma unroll 4
      for (int k = 0; k < 256; k += 4) {
        float4 hv = *(const float4*)(hp + k);
        const float* w = wh + (size_t)k * 1024;
        float4 w0 = *(const float4*)(w);
        float4 w1 = *(const float4*)(w + 1024);
        float4 w2 = *(const float4*)(w + 2048);
        float4 w3 = *(const float4*)(w + 3072);
        gi += hv.x * w0.x + hv.y * w1.x + hv.z * w2.x + hv.w * w3.x;
        gf += hv.x * w0.y + hv.y * w1.y + hv.z * w2.y + hv.w * w3.y;
        gg += hv.x * w0.z + hv.y * w1.z + hv.z * w2.z + hv.w * w3.z;
        go += hv.x * w0.w + hv.y * w1.w + hv.z * w2.w + hv.w * w3.w;
      }
    }
    {
      const float* xp = &xL[sl][0];
#pragma unroll 4
      for (int k = 0; k < 256; k += 4) {
        float4 xv = *(const float4*)(xp + k);
        const float* w = wi + (size_t)k * 1024;
        float4 w0 = *(const float4*)(w);
        float4 w1 = *(const float4*)(w + 1024);
        float4 w2 = *(const float4*)(w + 2048);
        float4 w3 = *(const float4*)(w + 3072);
        gi += xv.x * w0.x + xv.y * w1.x + xv.z * w2.x + xv.w * w3.x;
        gf += xv.x * w0.y + xv.y * w1.y + xv.z * w2.y + xv.w * w3.y;
        gg += xv.x * w0.z + xv.y * w1.z + xv.z * w2.z + xv.w * w3.z;
        go += xv.x * w0.w + xv.y * w1.w + xv.z * w2.w + xv.w * w3.w;
      }
    }
    float c_new = sigm(gf) * c + sigm(gi) * tanhfast(gg);
    c = c_new;
    float h = sigm(go) * tanhfast(c_new);
    __syncthreads();
    hL[sl][hid] = h;
    if (t + 1 < TT) {
      int tn = t + 1;
      xL[sl][hid] = hid < 128 ? xrow[tn * 128 + hid]
                              : xrow[tn * 128 + hid - 128] - srow[tn * 128 + hid - 128];
    }
    if (t == mylen - 1) fout[hid] = h;
    __syncthreads();
  }
}

__global__ __launch_bounds__(256) void finish_kernel(
    const float* __restrict__ ws, const float* __restrict__ W1,
    const float* __restrict__ b1, const float* __restrict__ W2,
    const float* __restrict__ b2, const float* __restrict__ W3,
    const float* __restrict__ b3, float* __restrict__ out) {
  __shared__ float oL[256];
  __shared__ float wsum[4];
  int tid = threadIdx.x;
  int p = blockIdx.x >> 5, b = blockIdx.x & 31;
  const float* fa = ws + FSEL_OFF + (size_t)((2 * p) * 32 + b) * 256;
  const float* fb = ws + FSEL_OFF + (size_t)((2 * p + 1) * 32 + b) * 256;
  oL[tid] = fa[tid];
  __syncthreads();
  float a1 = b1[tid], a2 = b2[tid], a3 = b3[tid];
  const float* w1r = W1 + tid * 256;
  const float* w2r = W2 + tid * 256;
  const float* w3r = W3 + tid * 256;
  for (int k = 0; k < 256; k++) {
    float ov = oL[k];
    a1 += ov * w1r[k];
    a2 += ov * w2r[k];
    a3 += ov * w3r[k];
  }
  float cg = sigm(a1) * leaky(a2);
  float res = oL[tid] + sigm(a3) * leaky(cg);
  float d = res - fb[tid] + 1e-6f;
  float sq = d * d;
  for (int m = 32; m >= 1; m >>= 1) sq += __shfl_down(sq, m, 64);
  if ((tid & 63) == 0) wsum[tid >> 6] = sq;
  __syncthreads();
  if (tid == 0) {
    float s = wsum[0] + wsum[1] + wsum[2] + wsum[3];
    out[p * BB + b] = expf(sqrtf(s));
  }
}

extern "C" void kernel_launch(void* const* d_in, const int* in_sizes, int n_in,
                              void* d_out, int out_size, void* d_ws, size_t ws_size,
                              hipStream_t stream) {
  const float* anchor = (const float*)d_in[0];
  const float* trajs = (const float*)d_in[1];
  const float* negat = (const float*)d_in[2];
  const int* la = (const int*)d_in[3];
  const int* lt = (const int*)d_in[4];
  const int* ln = (const int*)d_in[5];
  const float* Wm = (const float*)d_in[6];
  const float* bm = (const float*)d_in[7];
  const float* Wih = (const float*)d_in[8];
  const float* Whh = (const float*)d_in[9];
  const float* bih = (const float*)d_in[10];
  const float* bhh = (const float*)d_in[11];
  const float* W1 = (const float*)d_in[12];
  const float* b1 = (const float*)d_in[13];
  const float* W2 = (const float*)d_in[14];
  const float* b2 = (const float*)d_in[15];
  const float* W3 = (const float*)d_in[16];
  const float* b3 = (const float*)d_in[17];
  float* ws = (float*)d_ws;
  float* out = (float*)d_out;

  embed_kernel<<<(3 * BB * TT * 128) / 256, 256, 0, stream>>>(anchor, trajs, negat, Wm, bm, ws);
  mask_kernel<<<(3 * BB * TT) / 256, 256, 0, stream>>>(anchor, trajs, negat, ws);
  wt_kernel<<<2564, 256, 0, stream>>>(Wih, Whh, bih, bhh, ws);
  attn_kernel<<<4096, 256, 0, stream>>>(ws);

  // pick the largest xg chunk that fits the workspace
  size_t basebytes = XGBUF_OFF * sizeof(float);
  int CH = 0;
  const int cands[4] = {512, 256, 128, 64};
  for (int i = 0; i < 4; i++) {
    size_t need = basebytes + (size_t)cands[i] * 128 * 1024 * sizeof(float);
    if (need <= ws_size) { CH = cands[i]; break; }
  }
  if (CH) {
    int nch = TT / CH;
    int xgrid = 128 * ((CH >> 6) << 2);
    for (int c = 0; c < nch; c++) {
      int tc0 = c * CH;
      xg_kernel<<<xgrid, 256, 0, stream>>>(ws, tc0, CH, la, lt, ln);
      rec5_kernel<<<128, 512, 0, stream>>>(ws, la, lt, ln, tc0, CH);
    }
  } else {
    rec_fb_kernel<<<64, 512, 0, stream>>>(ws, la, lt, ln);
  }
  finish_kernel<<<64, 256, 0, stream>>>(ws, W1, b1, W2, b2, W3, b3, out);
}

// Round 8
// 1422.403 us; speedup vs baseline: 12.0437x; 1.6729x over previous
//
#include <hip/hip_runtime.h>

constexpr int BB = 32;
constexpr int TT = 512;
constexpr size_t MSZ = (size_t)BB * TT * 128;              // one embedding array (floats)
constexpr size_t M_OFF = 0;                                // 3 * MSZ
constexpr size_t MASK_OFF = 3 * MSZ;                       // 3*B*T ints
constexpr size_t SUM_OFF = MASK_OFF + (size_t)3 * BB * TT; // 4 * MSZ
constexpr size_t M16_OFF = SUM_OFF + 4 * MSZ;              // 3*MSZ fp16 -> 3*MSZ/2 dwords
constexpr size_t MT16_OFF = M16_OFF + 3 * MSZ / 2;         // transposed fp16 [d][t]
constexpr size_t WHH_OFF = MT16_OFF + 3 * MSZ / 2;         // 256*1024 floats [k][hid][gate]
constexpr size_t WIH_OFF = WHH_OFF + (size_t)256 * 1024;   // 256*1024 floats [k][hid][gate]
constexpr size_t BIAS_OFF = WIH_OFF + (size_t)256 * 1024;  // 1024 floats [hid][gate]
constexpr size_t W5_OFF = BIAS_OFF + 1024;                 // 131072 dwords fp16x2 Whh
constexpr size_t FSEL_OFF = W5_OFF + 131072;               // 128*256 floats [seq][hid]
constexpr size_t STATE_OFF = FSEL_OFF + (size_t)128 * 256; // h(32768) + c(32768) f32
constexpr size_t XGBUF_OFF = STATE_OFF + 65536;            // CH*128*1024 floats (chunked x-gates)

typedef _Float16 h2v __attribute__((ext_vector_type(2)));
typedef _Float16 half8 __attribute__((ext_vector_type(8)));
typedef float f32x4 __attribute__((ext_vector_type(4)));

__device__ __forceinline__ float sigm(float x) {
  return __builtin_amdgcn_rcpf(1.f + __builtin_amdgcn_exp2f(-1.44269504f * x));
}
__device__ __forceinline__ float tanhfast(float x) {
  float e = __builtin_amdgcn_exp2f(2.88539008f * x);
  return 1.f - 2.f * __builtin_amdgcn_rcpf(e + 1.f);
}
__device__ __forceinline__ float leaky(float x) { return x >= 0.f ? x : 0.1f * x; }

__device__ __forceinline__ unsigned int pack2h(float a, float b) {
  h2v h;
  h.x = (_Float16)a;
  h.y = (_Float16)b;
  return __builtin_bit_cast(unsigned int, h);
}

__device__ __forceinline__ float fdot2u(unsigned int a, unsigned int b, float c) {
#if __has_builtin(__builtin_amdgcn_fdot2)
  return __builtin_amdgcn_fdot2(__builtin_bit_cast(h2v, a), __builtin_bit_cast(h2v, b), c, false);
#else
  h2v ha = __builtin_bit_cast(h2v, a), hb = __builtin_bit_cast(h2v, b);
  return c + (float)ha.x * (float)hb.x + (float)ha.y * (float)hb.y;
#endif
}

#define GLOAD_LDS16(gp, lp)                                                    \
  __builtin_amdgcn_global_load_lds(                                            \
      (const __attribute__((address_space(1))) void*)(gp),                     \
      (__attribute__((address_space(3))) void*)(lp), 16, 0, 0)

__global__ __launch_bounds__(256) void embed_kernel(
    const float* __restrict__ a, const float* __restrict__ t,
    const float* __restrict__ n, const float* __restrict__ Wm,
    const float* __restrict__ bm, float* __restrict__ ws) {
  int idx = blockIdx.x * 256 + threadIdx.x;   // < 3*B*T*128
  int h = idx & 127;
  int bt = idx >> 7;
  int traj = bt / (BB * TT);
  int r = bt - traj * (BB * TT);
  const float* src = traj == 0 ? a : (traj == 1 ? t : n);
  float x0 = src[r * 4 + 0], x1 = src[r * 4 + 1];
  float v = x0 * Wm[2 * h] + x1 * Wm[2 * h + 1] + bm[h];
  ws[M_OFF + (size_t)traj * MSZ + (size_t)r * 128 + h] = leaky(v);
}

__global__ __launch_bounds__(256) void mask_kernel(
    const float* __restrict__ a, const float* __restrict__ t,
    const float* __restrict__ n, float* __restrict__ ws) {
  int idx = blockIdx.x * 256 + threadIdx.x;   // < 3*B*T
  int traj = idx / (BB * TT);
  int r = idx - traj * (BB * TT);
  const float* src = traj == 0 ? a : (traj == 1 ? t : n);
  float gx = src[r * 4 + 2], gy = src[r * 4 + 3];
  ((int*)(ws + MASK_OFF))[idx] = (gy * 128.f + gx - 257.f) >= 0.5f ? 1 : 0;
}

// fp16 copy of embeddings, [traj][b][t][d]
__global__ __launch_bounds__(256) void pack16_kernel(float* __restrict__ ws) {
  size_t idx = (size_t)blockIdx.x * 256 + threadIdx.x;   // < 3*MSZ/2
  float v0 = ws[M_OFF + 2 * idx];
  float v1 = ws[M_OFF + 2 * idx + 1];
  ((unsigned int*)ws)[M16_OFF + idx] = pack2h(v0, v1);
}

// transposed fp16 copy, [traj][b][d][t]
__global__ __launch_bounds__(256) void packT_kernel(float* __restrict__ ws) {
  __shared__ float L[64][130];
  int tid = threadIdx.x;
  int traj = blockIdx.x >> 5, b = blockIdx.x & 31;
  const float* src = ws + M_OFF + (size_t)traj * MSZ + (size_t)b * TT * 128;
  size_t basedw = ((size_t)traj * MSZ + (size_t)b * TT * 128) >> 1;
  unsigned int* dst = (unsigned int*)ws + MT16_OFF + basedw;
  for (int tt = 0; tt < 8; tt++) {
    int t0 = tt * 64;
    __syncthreads();
#pragma unroll
    for (int i = 0; i < 32; i++) {
      int idx = i * 256 + tid;
      int tl = idx >> 7, d = idx & 127;
      L[tl][d] = src[(size_t)(t0 + tl) * 128 + d];
    }
    __syncthreads();
#pragma unroll
    for (int i = 0; i < 16; i++) {
      int j = i * 256 + tid;
      int d = j >> 5, tp = j & 31;
      dst[(size_t)d * 256 + (t0 >> 1) + tp] = pack2h(L[2 * tp][d], L[2 * tp + 1][d]);
    }
  }
}

// transpose Whh/Wih to [k][hid][gate]; fold biases; emit packed-fp16 W5 for rec5
__global__ __launch_bounds__(256) void wt_kernel(
    const float* __restrict__ Wih, const float* __restrict__ Whh,
    const float* __restrict__ bih, const float* __restrict__ bhh,
    float* __restrict__ ws) {
  int idx = blockIdx.x * 256 + threadIdx.x;  // < 656384
  if (idx < 262144) {
    int k = idx >> 10;
    int rest = idx & 1023;
    int hid = rest >> 2, g = rest & 3;
    ws[WHH_OFF + idx] = Whh[(g * 256 + hid) * 256 + k];
  } else if (idx < 524288) {
    int j = idx - 262144;
    int k = j >> 10;
    int rest = j & 1023;
    int hid = rest >> 2, g = rest & 3;
    ws[WIH_OFF + j] = Wih[(g * 256 + hid) * 256 + k];
  } else if (idx < 525312) {
    int j = idx - 524288;
    int hid = j >> 2, g = j & 3;
    ws[BIAS_OFF + j] = bih[g * 256 + hid] + bhh[g * 256 + hid];
  } else if (idx < 656384) {
    int j = idx - 525312;
    int u = j & 3;
    int hid = (j >> 2) & 255;
    int g = (j >> 10) & 15;
    int gate = (j >> 14) & 3;
    int kh = j >> 16;
    int k0 = kh * 128 + g * 8 + u * 2;
    const float* row = Whh + (size_t)(gate * 256 + hid) * 256;
    ((unsigned int*)ws)[W5_OFF + j] = pack2h(row[k0], row[k0 + 1]);
  }
}

// MFMA attention: WG = (job, b, 32-row t-tile). 2048 WGs x 256 thr.
// Scores: S^T = mb @ ma^T via mfma_f32_16x16x32_f16 (both frags row-major reads).
// PV: out = P @ mb with B from transposed global copy mT16.
// LDS staging via global_load_lds with XOR-swizzled (slot^=row&7, 16B granules) source.
__global__ __launch_bounds__(256) void attn2_kernel(float* __restrict__ ws) {
  __shared__ _Float16 srcL[32 * 128];    // ma rows, swizzled, 8 KB
  __shared__ _Float16 dbuf[128 * 128];   // mb / mbT chunk, swizzled, 32 KB
  __shared__ float scf[32 * 521];        // scores f32, padded, 66.7 KB
  __shared__ _Float16 p16[32 * 512];     // probabilities fp16, swizzled, 32 KB
  __shared__ float rowscale[32];
  __shared__ int mD[512];
  __shared__ int mS[32];

  int tid = threadIdx.x;
  int w = tid >> 6, lane = tid & 63;
  int l15 = lane & 15, l4 = lane >> 4;
  int bid = blockIdx.x;
  int job = bid >> 9;
  int rem = bid & 511;
  int b = rem >> 4, tb = rem & 15;
  int t0 = tb * 32;
  int srcTr = (job == 1) ? 1 : ((job == 3) ? 2 : 0);
  int dstTr = (job == 0) ? 1 : ((job == 2) ? 2 : 0);
  const _Float16* m16 = (const _Float16*)((const unsigned int*)ws + M16_OFF);
  const _Float16* mT16 = (const _Float16*)((const unsigned int*)ws + MT16_OFF);
  const _Float16* srcb = m16 + (size_t)srcTr * MSZ + (size_t)b * TT * 128;
  const _Float16* dstb = m16 + (size_t)dstTr * MSZ + (size_t)b * TT * 128;
  const _Float16* dstbT = mT16 + (size_t)dstTr * MSZ + (size_t)b * TT * 128;
  const int* maskbase = (const int*)(ws + MASK_OFF);
  const int* smask = maskbase + srcTr * BB * TT + b * TT;
  const int* dmask = maskbase + dstTr * BB * TT + b * TT;
  float* out = ws + SUM_OFF + (size_t)job * MSZ + (size_t)b * TT * 128;

  // stage srcL (32 rows x 128 d fp16), source-swizzled
#pragma unroll
  for (int i = 0; i < 2; i++) {
    int inst = w * 2 + i;
    int tl = inst * 4 + l4;
    const char* sp = (const char*)(srcb + (size_t)(t0 + tl) * 128) + ((l15 ^ (tl & 7)) << 4);
    GLOAD_LDS16(sp, (char*)srcL + inst * 1024);
  }
  mD[tid] = dmask[tid];                 // FIX R7: fill BOTH halves (256 threads only)
  mD[tid + 256] = dmask[tid + 256];
  if (tid < 32) mS[tid] = smask[t0 + tid];

  // ---- phase A: scores ----
  for (int sc = 0; sc < 4; sc++) {
    int s0 = sc * 128;
    __syncthreads();
#pragma unroll
    for (int i = 0; i < 8; i++) {
      int inst = w * 8 + i;
      int rl = inst * 4 + l4;
      const char* sp = (const char*)(dstb + (size_t)(s0 + rl) * 128) + ((l15 ^ (rl & 7)) << 4);
      GLOAD_LDS16(sp, (char*)dbuf + inst * 1024);
    }
    __syncthreads();

    f32x4 c[2][2] = {{{0.f, 0.f, 0.f, 0.f}, {0.f, 0.f, 0.f, 0.f}},
                     {{0.f, 0.f, 0.f, 0.f}, {0.f, 0.f, 0.f, 0.f}}};
#pragma unroll
    for (int kk = 0; kk < 4; kk++) {
      int gc = kk * 4 + l4;
      half8 afr[2], bfr[2];
#pragma unroll
      for (int si = 0; si < 2; si++) {
        int srow = (w * 2 + si) * 16 + l15;
        afr[si] = *(const half8*)(dbuf + srow * 128 + ((gc ^ (srow & 7)) << 3));
      }
#pragma unroll
      for (int ti = 0; ti < 2; ti++) {
        int trow = ti * 16 + l15;
        bfr[ti] = *(const half8*)(srcL + trow * 128 + ((gc ^ (trow & 7)) << 3));
      }
#pragma unroll
      for (int si = 0; si < 2; si++)
#pragma unroll
        for (int ti = 0; ti < 2; ti++)
          c[si][ti] = __builtin_amdgcn_mfma_f32_16x16x32_f16(afr[si], bfr[ti], c[si][ti], 0, 0, 0);
    }
    // scatter with dst mask (exact -1e9 semantics)
#pragma unroll
    for (int si = 0; si < 2; si++)
#pragma unroll
      for (int ti = 0; ti < 2; ti++) {
        int tl = ti * 16 + l15;
#pragma unroll
        for (int r = 0; r < 4; r++) {
          int sg = s0 + (w * 2 + si) * 16 + l4 * 4 + r;
          scf[tl * 521 + sg] = mD[sg] ? c[si][ti][r] : -1e9f;
        }
      }
  }
  __syncthreads();

  // ---- softmax (8 threads per row) ----
  {
    int row = tid >> 3, j = tid & 7;
    const float* sr = &scf[row * 521];
    float mx = -3.0e38f;
#pragma unroll 8
    for (int i = 0; i < 64; i++) mx = fmaxf(mx, sr[j + 8 * i]);
    for (int m = 1; m <= 4; m <<= 1) mx = fmaxf(mx, __shfl_xor(mx, m, 64));
    float den = 0.f;
    float* srw = &scf[row * 521];
#pragma unroll 8
    for (int i = 0; i < 64; i++) {
      float p = __builtin_amdgcn_exp2f((srw[j + 8 * i] - mx) * 1.44269504f);
      srw[j + 8 * i] = p;
      den += p;
    }
    for (int m = 1; m <= 4; m <<= 1) den += __shfl_xor(den, m, 64);
    if (j == 0) rowscale[row] = (mS[row] && mx > -5e8f) ? (1.f / den) : 0.f;
  }
  __syncthreads();

  // ---- convert P to swizzled fp16 ----
#pragma unroll
  for (int i = 0; i < 64; i++) {
    int idx = i * 256 + tid;
    int t = idx >> 9, s = idx & 511;
    int gp = ((s >> 3) ^ (t & 7));
    p16[t * 512 + gp * 8 + (s & 7)] = (_Float16)scf[t * 521 + s];
  }

  // ---- phase B: PV ----
  f32x4 o[2][2] = {{{0.f, 0.f, 0.f, 0.f}, {0.f, 0.f, 0.f, 0.f}},
                   {{0.f, 0.f, 0.f, 0.f}, {0.f, 0.f, 0.f, 0.f}}};
  for (int sc = 0; sc < 4; sc++) {
    int s0 = sc * 128;
    __syncthreads();
#pragma unroll
    for (int i = 0; i < 8; i++) {
      int inst = w * 8 + i;
      int rd = inst * 4 + l4;
      const char* sp = (const char*)(dstbT + (size_t)rd * 512 + s0) + ((l15 ^ (rd & 7)) << 4);
      GLOAD_LDS16(sp, (char*)dbuf + inst * 1024);
    }
    __syncthreads();
#pragma unroll
    for (int ks = 0; ks < 4; ks++) {
      int gc = ks * 4 + l4;
      half8 afr[2], bfr[2];
#pragma unroll
      for (int ti = 0; ti < 2; ti++) {
        int t = ti * 16 + l15;
        int sg = sc * 16 + gc;
        afr[ti] = *(const half8*)(p16 + t * 512 + ((sg ^ (t & 7)) << 3));
      }
#pragma unroll
      for (int di = 0; di < 2; di++) {
        int d = (w * 2 + di) * 16 + l15;
        bfr[di] = *(const half8*)(dbuf + d * 128 + ((gc ^ (d & 7)) << 3));
      }
#pragma unroll
      for (int ti = 0; ti < 2; ti++)
#pragma unroll
        for (int di = 0; di < 2; di++)
          o[ti][di] = __builtin_amdgcn_mfma_f32_16x16x32_f16(afr[ti], bfr[di], o[ti][di], 0, 0, 0);
    }
  }
  // epilogue: scale by rowscale, store
#pragma unroll
  for (int ti = 0; ti < 2; ti++)
#pragma unroll
    for (int di = 0; di < 2; di++) {
      int dglob = (w * 2 + di) * 16 + l15;
#pragma unroll
      for (int r = 0; r < 4; r++) {
        int tl = ti * 16 + l4 * 4 + r;
        out[(size_t)(t0 + tl) * 128 + dglob] = o[ti][di][r] * rowscale[tl];
      }
    }
}

// chunked x-gate GEMM: xg[seq][t-tc0][1024] = xcat @ WihT + bias (fp32)
__global__ __launch_bounds__(256) void xg_kernel(
    float* __restrict__ ws, int tc0, int CH,
    const int* __restrict__ la, const int* __restrict__ lt, const int* __restrict__ ln) {
  __shared__ float aT[32][68];
  __shared__ float bL[32][256];
  int tid = threadIdx.x;
  int bx = blockIdx.x;
  int tt4 = (CH >> 6) << 2;       // tiles*4 per seq
  int seq = bx / tt4;
  int rem = bx - seq * tt4;
  int tt = rem >> 2;
  int nc = rem & 3;
  int t0 = tc0 + tt * 64;
  int l = seq >> 5, b = seq & 31;
  const int* lens = (l == 1) ? lt : ((l == 3) ? ln : la);
  if (t0 >= lens[b]) return;
  int srcTr = (l == 1) ? 1 : ((l == 3) ? 2 : 0);
  const float* xrow = ws + M_OFF + (size_t)srcTr * MSZ + (size_t)b * TT * 128;
  const float* srow = ws + SUM_OFF + (size_t)l * MSZ + (size_t)b * TT * 128;

  int r0 = tid >> 5;
  int c0 = (tid & 31) * 4;

  float acc[8][8];
#pragma unroll
  for (int i = 0; i < 8; i++)
#pragma unroll
    for (int j = 0; j < 8; j++) acc[i][j] = 0.f;

  for (int kc = 0; kc < 8; kc++) {
    int kbase = kc * 32;
    __syncthreads();
#pragma unroll
    for (int i = 0; i < 8; i++) {
      int idx = i * 256 + tid;
      int m = idx >> 5, kkv = idx & 31;
      float v;
      if (kbase < 128) {
        v = xrow[(size_t)(t0 + m) * 128 + kbase + kkv];
      } else {
        int k2 = kbase + kkv - 128;
        v = xrow[(size_t)(t0 + m) * 128 + k2] - srow[(size_t)(t0 + m) * 128 + k2];
      }
      aT[kkv][m] = v;
    }
#pragma unroll
    for (int i = 0; i < 32; i++) {
      int idx = i * 256 + tid;
      int kkv = idx >> 8, n = idx & 255;
      bL[kkv][n] = ws[WIH_OFF + (size_t)(kbase + kkv) * 1024 + nc * 256 + n];
    }
    __syncthreads();
#pragma unroll 2
    for (int kkv = 0; kkv < 32; kkv++) {
      float4 a0 = *(const float4*)&aT[kkv][r0 * 8];
      float4 a1 = *(const float4*)&aT[kkv][r0 * 8 + 4];
      float4 b0 = *(const float4*)&bL[kkv][c0];
      float4 b1 = *(const float4*)&bL[kkv][c0 + 128];
      float av[8] = {a0.x, a0.y, a0.z, a0.w, a1.x, a1.y, a1.z, a1.w};
      float bv[8] = {b0.x, b0.y, b0.z, b0.w, b1.x, b1.y, b1.z, b1.w};
#pragma unroll
      for (int i = 0; i < 8; i++)
#pragma unroll
        for (int j = 0; j < 8; j++) acc[i][j] += av[i] * bv[j];
    }
  }

  float4 bias0 = *(const float4*)&ws[BIAS_OFF + nc * 256 + c0];
  float4 bias1 = *(const float4*)&ws[BIAS_OFF + nc * 256 + c0 + 128];
#pragma unroll
  for (int i = 0; i < 8; i++) {
    int tl = t0 - tc0 + r0 * 8 + i;
    float* o = ws + XGBUF_OFF + ((size_t)seq * CH + tl) * 1024 + nc * 256 + c0;
    float4 v0 = {acc[i][0] + bias0.x, acc[i][1] + bias0.y,
                 acc[i][2] + bias0.z, acc[i][3] + bias0.w};
    float4 v1 = {acc[i][4] + bias1.x, acc[i][5] + bias1.y,
                 acc[i][6] + bias1.z, acc[i][7] + bias1.w};
    *(float4*)o = v0;
    *(float4*)(o + 128) = v1;
  }
}

// CU-resident recurrence (proven R6): 128 WGs x 512 thr, 1 seq/WG.
__global__ __launch_bounds__(512, 2) void rec5_kernel(
    float* __restrict__ ws, const int* __restrict__ la,
    const int* __restrict__ lt, const int* __restrict__ ln,
    int t0c, int CH) {
  __shared__ unsigned int o_w[32768];   // [kh][g][hid][u] -> 128KB
  __shared__ unsigned int hp[128];      // h as fp16x2
  __shared__ float4 part[256];          // kh=1 partial gate sums
  int tid = threadIdx.x;
  int hid = tid & 255;
  int kh = tid >> 8;
  int seq = blockIdx.x;
  int l = seq >> 5, b = seq & 31;
  int mylen = (l == 1) ? lt[b] : ((l == 3) ? ln[b] : la[b]);
  int tend = min(CH, mylen - t0c);
  if (tend <= 0) return;

  const unsigned int* W5 = (const unsigned int*)ws + W5_OFF;

  uint4 wi[16], wf[16], wg[16];
  {
    const unsigned int* base = W5 + (size_t)kh * 65536 + hid * 4;
#pragma unroll
    for (int g = 0; g < 16; g++) {
      wi[g] = *(const uint4*)(base + (0 * 16 + g) * 1024);
      wf[g] = *(const uint4*)(base + (1 * 16 + g) * 1024);
      wg[g] = *(const uint4*)(base + (2 * 16 + g) * 1024);
    }
  }
  {
    int wv = tid >> 6;
    int khw = wv >> 2;
    int hidbase = (wv & 3) * 64;
    const unsigned int* srcb = W5 + (size_t)(khw * 4 + 3) * 16384 + (hidbase + (tid & 63)) * 4;
#pragma unroll
    for (int g = 0; g < 16; g++) {
      GLOAD_LDS16(srcb + g * 1024, &o_w[((khw * 16 + g) * 256 + hidbase) * 4]);
    }
  }

  float c_st = 0.f, hlast = 0.f;
  if (t0c == 0) {
    if (tid < 128) hp[tid] = 0u;
  } else {
    if (tid < 128) {
      float h0 = ws[STATE_OFF + (size_t)seq * 256 + 2 * tid];
      float h1 = ws[STATE_OFF + (size_t)seq * 256 + 2 * tid + 1];
      hp[tid] = pack2h(h0, h1);
    }
    if (kh == 0) {
      hlast = ws[STATE_OFF + (size_t)seq * 256 + hid];
      c_st = ws[STATE_OFF + 32768 + (size_t)seq * 256 + hid];
    }
  }
  const float* xgrow = ws + XGBUF_OFF + ((size_t)seq * CH) * 1024 + hid * 4;
  float* fout = ws + FSEL_OFF + (size_t)seq * 256;
  __syncthreads();

  for (int tl = 0; tl < tend; tl++) {
    float ai = 0.f, af = 0.f, ag = 0.f, ao = 0.f;
    const unsigned int* hb = &hp[kh * 64];
#pragma unroll
    for (int g = 0; g < 16; g++) {
      uint4 h4 = *(const uint4*)(hb + g * 4);
      uint4 o4 = *(const uint4*)&o_w[((kh * 16 + g) * 256 + hid) * 4];
      ai = fdot2u(wi[g].x, h4.x, ai); ai = fdot2u(wi[g].y, h4.y, ai);
      ai = fdot2u(wi[g].z, h4.z, ai); ai = fdot2u(wi[g].w, h4.w, ai);
      af = fdot2u(wf[g].x, h4.x, af); af = fdot2u(wf[g].y, h4.y, af);
      af = fdot2u(wf[g].z, h4.z, af); af = fdot2u(wf[g].w, h4.w, af);
      ag = fdot2u(wg[g].x, h4.x, ag); ag = fdot2u(wg[g].y, h4.y, ag);
      ag = fdot2u(wg[g].z, h4.z, ag); ag = fdot2u(wg[g].w, h4.w, ag);
      ao = fdot2u(o4.x, h4.x, ao); ao = fdot2u(o4.y, h4.y, ao);
      ao = fdot2u(o4.z, h4.z, ao); ao = fdot2u(o4.w, h4.w, ao);
    }
    if (kh == 1) part[hid] = make_float4(ai, af, ag, ao);
    __syncthreads();
    if (kh == 0) {
      float4 p2 = part[hid];
      float4 xv = *(const float4*)(xgrow + (size_t)tl * 1024);
      float gi = ai + p2.x + xv.x;
      float gf = af + p2.y + xv.y;
      float gg = ag + p2.z + xv.z;
      float go_ = ao + p2.w + xv.w;
      c_st = sigm(gf) * c_st + sigm(gi) * tanhfast(gg);
      float h = sigm(go_) * tanhfast(c_st);
      hlast = h;
      ((_Float16*)hp)[hid] = (_Float16)h;
      if (t0c + tl == mylen - 1) fout[hid] = h;
    }
    __syncthreads();
  }
  if (kh == 0) {
    ws[STATE_OFF + (size_t)seq * 256 + hid] = hlast;
    ws[STATE_OFF + 32768 + (size_t)seq * 256 + hid] = c_st;
  }
}

// fallback if ws too small for chunked xg
__global__ __launch_bounds__(512, 2) void rec_fb_kernel(
    float* __restrict__ ws, const int* __restrict__ la,
    const int* __restrict__ lt, const int* __restrict__ ln) {
  __shared__ float hL[2][256];
  __shared__ float xL[2][256];
  int tid = threadIdx.x;
  int sl = tid >> 8;
  int hid = tid & 255;
  int seq = blockIdx.x * 2 + sl;
  int l = seq >> 5, b = seq & 31;
  int srcTr = (l == 1) ? 1 : ((l == 3) ? 2 : 0);
  const float* xrow = ws + M_OFF + (size_t)srcTr * MSZ + (size_t)b * TT * 128;
  const float* srow = ws + SUM_OFF + (size_t)l * MSZ + (size_t)b * TT * 128;
  const int* lens = (l == 1) ? lt : ((l == 3) ? ln : la);
  int mylen = lens[b];
  const float* wh = ws + WHH_OFF + (hid << 2);
  const float* wi = ws + WIH_OFF + (hid << 2);
  float4 biasv = *(const float4*)&ws[BIAS_OFF + (hid << 2)];
  float c = 0.f;
  hL[sl][hid] = 0.f;
  xL[sl][hid] = hid < 128 ? xrow[hid] : xrow[hid - 128] - srow[hid - 128];
  __syncthreads();
  float* fout = ws + FSEL_OFF + (size_t)seq * 256;

  for (int t = 0; t < TT; t++) {
    float gi = biasv.x, gf = biasv.y, gg = biasv.z, go = biasv.w;
    {
      const float* hp = &hL[sl][0];
#pragma unroll 4
      for (int k = 0; k < 256; k += 4) {
        float4 hv = *(const float4*)(hp + k);
        const float* w = wh + (size_t)k * 1024;
        float4 w0 = *(const float4*)(w);
        float4 w1 = *(const float4*)(w + 1024);
        float4 w2 = *(const float4*)(w + 2048);
        float4 w3 = *(const float4*)(w + 3072);
        gi += hv.x * w0.x + hv.y * w1.x + hv.z * w2.x + hv.w * w3.x;
        gf += hv.x * w0.y + hv.y * w1.y + hv.z * w2.y + hv.w * w3.y;
        gg += hv.x * w0.z + hv.y * w1.z + hv.z * w2.z + hv.w * w3.z;
        go += hv.x * w0.w + hv.y * w1.w + hv.z * w2.w + hv.w * w3.w;
      }
    }
    {
      const float* xp = &xL[sl][0];
#pragma unroll 4
      for (int k = 0; k < 256; k += 4) {
        float4 xv = *(const float4*)(xp + k);
        const float* w = wi + (size_t)k * 1024;
        float4 w0 = *(const float4*)(w);
        float4 w1 = *(const float4*)(w + 1024);
        float4 w2 = *(const float4*)(w + 2048);
        float4 w3 = *(const float4*)(w + 3072);
        gi += xv.x * w0.x + xv.y * w1.x + xv.z * w2.x + xv.w * w3.x;
        gf += xv.x * w0.y + xv.y * w1.y + xv.z * w2.y + xv.w * w3.y;
        gg += xv.x * w0.z + xv.y * w1.z + xv.z * w2.z + xv.w * w3.z;
        go += xv.x * w0.w + xv.y * w1.w + xv.z * w2.w + xv.w * w3.w;
      }
    }
    float c_new = sigm(gf) * c + sigm(gi) * tanhfast(gg);
    c = c_new;
    float h = sigm(go) * tanhfast(c_new);
    __syncthreads();
    hL[sl][hid] = h;
    if (t + 1 < TT) {
      int tn = t + 1;
      xL[sl][hid] = hid < 128 ? xrow[tn * 128 + hid]
                              : xrow[tn * 128 + hid - 128] - srow[tn * 128 + hid - 128];
    }
    if (t == mylen - 1) fout[hid] = h;
    __syncthreads();
  }
}

__global__ __launch_bounds__(256) void finish_kernel(
    const float* __restrict__ ws, const float* __restrict__ W1,
    const float* __restrict__ b1, const float* __restrict__ W2,
    const float* __restrict__ b2, const float* __restrict__ W3,
    const float* __restrict__ b3, float* __restrict__ out) {
  __shared__ float oL[256];
  __shared__ float wsum[4];
  int tid = threadIdx.x;
  int p = blockIdx.x >> 5, b = blockIdx.x & 31;
  const float* fa = ws + FSEL_OFF + (size_t)((2 * p) * 32 + b) * 256;
  const float* fb = ws + FSEL_OFF + (size_t)((2 * p + 1) * 32 + b) * 256;
  oL[tid] = fa[tid];
  __syncthreads();
  float a1 = b1[tid], a2 = b2[tid], a3 = b3[tid];
  const float* w1r = W1 + tid * 256;
  const float* w2r = W2 + tid * 256;
  const float* w3r = W3 + tid * 256;
  for (int k = 0; k < 256; k++) {
    float ov = oL[k];
    a1 += ov * w1r[k];
    a2 += ov * w2r[k];
    a3 += ov * w3r[k];
  }
  float cg = sigm(a1) * leaky(a2);
  float res = oL[tid] + sigm(a3) * leaky(cg);
  float d = res - fb[tid] + 1e-6f;
  float sq = d * d;
  for (int m = 32; m >= 1; m >>= 1) sq += __shfl_down(sq, m, 64);
  if ((tid & 63) == 0) wsum[tid >> 6] = sq;
  __syncthreads();
  if (tid == 0) {
    float s = wsum[0] + wsum[1] + wsum[2] + wsum[3];
    out[p * BB + b] = expf(sqrtf(s));
  }
}

extern "C" void kernel_launch(void* const* d_in, const int* in_sizes, int n_in,
                              void* d_out, int out_size, void* d_ws, size_t ws_size,
                              hipStream_t stream) {
  const float* anchor = (const float*)d_in[0];
  const float* trajs = (const float*)d_in[1];
  const float* negat = (const float*)d_in[2];
  const int* la = (const int*)d_in[3];
  const int* lt = (const int*)d_in[4];
  const int* ln = (const int*)d_in[5];
  const float* Wm = (const float*)d_in[6];
  const float* bm = (const float*)d_in[7];
  const float* Wih = (const float*)d_in[8];
  const float* Whh = (const float*)d_in[9];
  const float* bih = (const float*)d_in[10];
  const float* bhh = (const float*)d_in[11];
  const float* W1 = (const float*)d_in[12];
  const float* b1 = (const float*)d_in[13];
  const float* W2 = (const float*)d_in[14];
  const float* b2 = (const float*)d_in[15];
  const float* W3 = (const float*)d_in[16];
  const float* b3 = (const float*)d_in[17];
  float* ws = (float*)d_ws;
  float* out = (float*)d_out;

  embed_kernel<<<(3 * BB * TT * 128) / 256, 256, 0, stream>>>(anchor, trajs, negat, Wm, bm, ws);
  mask_kernel<<<(3 * BB * TT) / 256, 256, 0, stream>>>(anchor, trajs, negat, ws);
  pack16_kernel<<<(int)(3 * MSZ / 2 / 256), 256, 0, stream>>>(ws);
  packT_kernel<<<96, 256, 0, stream>>>(ws);
  wt_kernel<<<2564, 256, 0, stream>>>(Wih, Whh, bih, bhh, ws);
  attn2_kernel<<<2048, 256, 0, stream>>>(ws);

  // pick the largest xg chunk that fits the workspace
  size_t basebytes = XGBUF_OFF * sizeof(float);
  int CH = 0;
  const int cands[4] = {512, 256, 128, 64};
  for (int i = 0; i < 4; i++) {
    size_t need = basebytes + (size_t)cands[i] * 128 * 1024 * sizeof(float);
    if (need <= ws_size) { CH = cands[i]; break; }
  }
  if (CH) {
    int nch = TT / CH;
    int xgrid = 128 * ((CH >> 6) << 2);
    for (int c = 0; c < nch; c++) {
      int tc0 = c * CH;
      xg_kernel<<<xgrid, 256, 0, stream>>>(ws, tc0, CH, la, lt, ln);
      rec5_kernel<<<128, 512, 0, stream>>>(ws, la, lt, ln, tc0, CH);
    }
  } else {
    rec_fb_kernel<<<64, 512, 0, stream>>>(ws, la, lt, ln);
  }
  finish_kernel<<<64, 256, 0, stream>>>(ws, W1, b1, W2, b2, W3, b3, out);
}